// Round 1
// baseline (482.073 us; speedup 1.0000x reference)
//
#include <hip/hip_runtime.h>
#include <hip/hip_bf16.h>
#include <cstdint>
#include <cstddef>

#define DM 1024
#define NH 16
#define DH 64
#define BQ 1024
#define TT 4096
#define BB 4

using f32x4 = __attribute__((ext_vector_type(4))) float;
using s16x8 = __attribute__((ext_vector_type(8))) short;

__device__ __forceinline__ unsigned short f2bf(float f) {
  union { float f; unsigned int u; } v; v.f = f;
  unsigned int u = v.u;
  unsigned int r = (u + 0x7FFFu + ((u >> 16) & 1u)) >> 16;
  return (unsigned short)r;
}

__global__ void cvt_f32_bf16(const float* __restrict__ in, unsigned short* __restrict__ out, int n4) {
  int i = blockIdx.x * blockDim.x + threadIdx.x;
  if (i < n4) {
    float4 v = reinterpret_cast<const float4*>(in)[i];
    ushort4 o;
    o.x = f2bf(v.x); o.y = f2bf(v.y); o.z = f2bf(v.z); o.w = f2bf(v.w);
    reinterpret_cast<ushort4*>(out)[i] = o;
  }
}

__device__ __forceinline__ void gload_lds16(const unsigned short* g, unsigned short* l) {
  __builtin_amdgcn_global_load_lds(
      (const __attribute__((address_space(1))) unsigned int*)g,
      (__attribute__((address_space(3))) unsigned int*)l,
      16, 0, 0);
}

// C[m,n] = sum_k A[m,k] * W[n,k]   (A: Mx1024 bf16, W: 1024x1024 bf16, row-major)
// MODE 0: write bf16 scattered to [B, NH, SEQ, DH];  MODE 1: write f32 row-major [M, 1024]
template<int MODE, int SEQ>
__global__ __launch_bounds__(256) void gemm_bt(const unsigned short* __restrict__ A,
                                               const unsigned short* __restrict__ W,
                                               unsigned short* __restrict__ Cb,
                                               float* __restrict__ Cf) {
  __shared__ unsigned short As[128 * 32];
  __shared__ unsigned short Bs[128 * 32];
  const int tid = threadIdx.x;
  const int wid = tid >> 6, lane = tid & 63;
  const int m0 = blockIdx.x * 128, n0 = blockIdx.y * 128;
  const int wr = wid >> 1, wc = wid & 1;
  const int fr = lane & 15;
  const int fk = (lane >> 4) * 8;

  f32x4 acc[4][4];
#pragma unroll
  for (int mt = 0; mt < 4; mt++)
#pragma unroll
    for (int nt = 0; nt < 4; nt++) acc[mt][nt] = f32x4{0.f, 0.f, 0.f, 0.f};

  const unsigned short* gA = A + (size_t)(m0 + wid * 32 + (lane >> 2)) * DM + (lane & 3) * 8;
  const unsigned short* gW = W + (size_t)(n0 + wid * 32 + (lane >> 2)) * DM + (lane & 3) * 8;
  unsigned short* lA0 = &As[(wid * 32) * 32];
  unsigned short* lA1 = &As[(wid * 32 + 16) * 32];
  unsigned short* lB0 = &Bs[(wid * 32) * 32];
  unsigned short* lB1 = &Bs[(wid * 32 + 16) * 32];

  for (int kt = 0; kt < DM / 32; ++kt) {
    gload_lds16(gA, lA0);
    gload_lds16(gA + 16 * DM, lA1);
    gload_lds16(gW, lB0);
    gload_lds16(gW + 16 * DM, lB1);
    gA += 32; gW += 32;
    __syncthreads();
    s16x8 af[4], bfv[4];
#pragma unroll
    for (int mt = 0; mt < 4; mt++)
      af[mt] = *reinterpret_cast<const s16x8*>(&As[(wr * 64 + mt * 16 + fr) * 32 + fk]);
#pragma unroll
    for (int nt = 0; nt < 4; nt++)
      bfv[nt] = *reinterpret_cast<const s16x8*>(&Bs[(wc * 64 + nt * 16 + fr) * 32 + fk]);
#pragma unroll
    for (int mt = 0; mt < 4; mt++)
#pragma unroll
      for (int nt = 0; nt < 4; nt++)
        acc[mt][nt] = __builtin_amdgcn_mfma_f32_16x16x32_bf16(af[mt], bfv[nt], acc[mt][nt], 0, 0, 0);
    __syncthreads();
  }

#pragma unroll
  for (int mt = 0; mt < 4; mt++) {
#pragma unroll
    for (int nt = 0; nt < 4; nt++) {
      const int col = n0 + wc * 64 + nt * 16 + fr;
#pragma unroll
      for (int r = 0; r < 4; r++) {
        const int m = m0 + wr * 64 + mt * 16 + (lane >> 4) * 4 + r;
        if constexpr (MODE == 0) {
          const int b = m / SEQ, sr = m % SEQ;
          const int h = col >> 6, dh = col & 63;
          Cb[((size_t)(b * NH + h) * SEQ + sr) * DH + dh] = f2bf(acc[mt][nt][r]);
        } else {
          Cf[(size_t)m * DM + col] = acc[mt][nt][r];
        }
      }
    }
  }
}

// Flash attention: Qp/Kp/Vp are [B, NH, seq, DH] bf16; Ob is [B, BQ, DM] bf16.
__global__ __launch_bounds__(256) void attn_kern(const unsigned short* __restrict__ Qp,
                                                 const unsigned short* __restrict__ Kp,
                                                 const unsigned short* __restrict__ Vp,
                                                 unsigned short* __restrict__ Ob) {
  __shared__ unsigned short Ks[64 * 64];
  __shared__ unsigned short Vt[64 * 64];
  __shared__ unsigned short Ps[4][16 * 64];
  const int bh = blockIdx.x;            // b*NH + h
  const int b = bh >> 4, h = bh & 15;
  const int q0 = blockIdx.y * 64;
  const int tid = threadIdx.x, wid = tid >> 6, lane = tid & 63;
  const int fr = lane & 15;
  const int fk = (lane >> 4) * 8;

  const size_t qbase = ((size_t)bh * BQ + q0 + wid * 16 + fr) * DH;
  s16x8 qf[2];
  qf[0] = *reinterpret_cast<const s16x8*>(&Qp[qbase + fk]);
  qf[1] = *reinterpret_cast<const s16x8*>(&Qp[qbase + 32 + fk]);

  f32x4 o[4];
  float mrun[4], lrun[4];
#pragma unroll
  for (int i = 0; i < 4; i++) { o[i] = f32x4{0.f, 0.f, 0.f, 0.f}; mrun[i] = -1e30f; lrun[i] = 0.f; }

  const size_t kvbase = (size_t)bh * TT * DH;
  const int strow = tid >> 3;   // 0..31
  const int stchk = tid & 7;    // 16B chunk

  for (int t0 = 0; t0 < TT; t0 += 64) {
    __syncthreads();
#pragma unroll
    for (int s = 0; s < 2; s++) {
      const int r = strow + s * 32;
      s16x8 kv = *reinterpret_cast<const s16x8*>(&Kp[kvbase + (size_t)(t0 + r) * DH + stchk * 8]);
      *reinterpret_cast<s16x8*>(&Ks[r * 64 + ((stchk * 8) ^ ((r & 7) << 3))]) = kv;
      s16x8 vv = *reinterpret_cast<const s16x8*>(&Vp[kvbase + (size_t)(t0 + r) * DH + stchk * 8]);
#pragma unroll
      for (int j = 0; j < 8; j++) {
        const int dh = stchk * 8 + j;
        Vt[dh * 64 + (r ^ ((dh & 7) << 3))] = (unsigned short)vv[j];
      }
    }
    __syncthreads();

    // S = q @ k^T  (rows: q-local, cols: t-local)
    f32x4 s4[4];
#pragma unroll
    for (int nt = 0; nt < 4; nt++) {
      s4[nt] = f32x4{0.f, 0.f, 0.f, 0.f};
      const int trow = nt * 16 + fr;
#pragma unroll
      for (int kc = 0; kc < 2; kc++) {
        s16x8 kb = *reinterpret_cast<const s16x8*>(&Ks[trow * 64 + ((kc * 32 + fk) ^ ((trow & 7) << 3))]);
        s4[nt] = __builtin_amdgcn_mfma_f32_16x16x32_bf16(qf[kc], kb, s4[nt], 0, 0, 0);
      }
    }

    const float scale = 0.125f;  // 1/sqrt(64)
    float tm[4];
#pragma unroll
    for (int r = 0; r < 4; r++)
      tm[r] = fmaxf(fmaxf(s4[0][r], s4[1][r]), fmaxf(s4[2][r], s4[3][r])) * scale;
#pragma unroll
    for (int d = 1; d < 16; d <<= 1)
#pragma unroll
      for (int r = 0; r < 4; r++) tm[r] = fmaxf(tm[r], __shfl_xor(tm[r], d));

    float al[4], ls[4];
#pragma unroll
    for (int r = 0; r < 4; r++) {
      float mn = fmaxf(mrun[r], tm[r]);
      al[r] = __expf(mrun[r] - mn);
      mrun[r] = mn;
      ls[r] = 0.f;
    }
#pragma unroll
    for (int nt = 0; nt < 4; nt++) {
#pragma unroll
      for (int r = 0; r < 4; r++) {
        float p = __expf(s4[nt][r] * scale - mrun[r]);
        ls[r] += p;
        const int row = (lane >> 4) * 4 + r;
        const int col = nt * 16 + fr;
        Ps[wid][row * 64 + (col ^ ((row & 7) << 3))] = f2bf(p);
      }
    }
#pragma unroll
    for (int d = 1; d < 16; d <<= 1)
#pragma unroll
      for (int r = 0; r < 4; r++) ls[r] += __shfl_xor(ls[r], d);
#pragma unroll
    for (int r = 0; r < 4; r++) lrun[r] = lrun[r] * al[r] + ls[r];
#pragma unroll
    for (int nt = 0; nt < 4; nt++)
#pragma unroll
      for (int r = 0; r < 4; r++) o[nt][r] *= al[r];

    // O += P @ V
    s16x8 pa[2];
#pragma unroll
    for (int kc = 0; kc < 2; kc++)
      pa[kc] = *reinterpret_cast<const s16x8*>(&Ps[wid][fr * 64 + ((kc * 32 + fk) ^ ((fr & 7) << 3))]);
#pragma unroll
    for (int nt = 0; nt < 4; nt++) {
      const int vrow = nt * 16 + fr;
#pragma unroll
      for (int kc = 0; kc < 2; kc++) {
        s16x8 vb = *reinterpret_cast<const s16x8*>(&Vt[vrow * 64 + ((kc * 32 + fk) ^ ((vrow & 7) << 3))]);
        o[nt] = __builtin_amdgcn_mfma_f32_16x16x32_bf16(pa[kc], vb, o[nt], 0, 0, 0);
      }
    }
  }

#pragma unroll
  for (int nt = 0; nt < 4; nt++) {
#pragma unroll
    for (int r = 0; r < 4; r++) {
      const int qr = q0 + wid * 16 + (lane >> 4) * 4 + r;
      const int col = h * DH + nt * 16 + fr;
      Ob[((size_t)b * BQ + qr) * DM + col] = f2bf(o[nt][r] / lrun[r]);
    }
  }
}

extern "C" void kernel_launch(void* const* d_in, const int* in_sizes, int n_in,
                              void* d_out, int out_size, void* d_ws, size_t ws_size,
                              hipStream_t stream) {
  const float* q_in = (const float*)d_in[0];
  const float* kv_in = (const float*)d_in[1];
  const float* Wq = (const float*)d_in[2];
  const float* Wk = (const float*)d_in[3];
  const float* Wv = (const float*)d_in[4];
  const float* Wo = (const float*)d_in[5];
  float* out = (float*)d_out;

  char* ws = (char*)d_ws;
  unsigned short* qin_b = (unsigned short*)ws;  ws += (size_t)BB * BQ * DM * 2;
  unsigned short* kvin_b = (unsigned short*)ws; ws += (size_t)BB * TT * DM * 2;
  unsigned short* Wq_b = (unsigned short*)ws;   ws += (size_t)DM * DM * 2;
  unsigned short* Wk_b = (unsigned short*)ws;   ws += (size_t)DM * DM * 2;
  unsigned short* Wv_b = (unsigned short*)ws;   ws += (size_t)DM * DM * 2;
  unsigned short* Wo_b = (unsigned short*)ws;   ws += (size_t)DM * DM * 2;
  unsigned short* qp = (unsigned short*)ws;     ws += (size_t)BB * NH * BQ * DH * 2;
  unsigned short* kp = (unsigned short*)ws;     ws += (size_t)BB * NH * TT * DH * 2;
  unsigned short* vp = (unsigned short*)ws;     ws += (size_t)BB * NH * TT * DH * 2;
  unsigned short* ao = (unsigned short*)ws;     ws += (size_t)BB * BQ * DM * 2;

  const int qn4 = BB * BQ * DM / 4;
  const int kvn4 = BB * TT * DM / 4;
  const int wn4 = DM * DM / 4;
  cvt_f32_bf16<<<(qn4 + 255) / 256, 256, 0, stream>>>(q_in, qin_b, qn4);
  cvt_f32_bf16<<<(kvn4 + 255) / 256, 256, 0, stream>>>(kv_in, kvin_b, kvn4);
  cvt_f32_bf16<<<(wn4 + 255) / 256, 256, 0, stream>>>(Wq, Wq_b, wn4);
  cvt_f32_bf16<<<(wn4 + 255) / 256, 256, 0, stream>>>(Wk, Wk_b, wn4);
  cvt_f32_bf16<<<(wn4 + 255) / 256, 256, 0, stream>>>(Wv, Wv_b, wn4);
  cvt_f32_bf16<<<(wn4 + 255) / 256, 256, 0, stream>>>(Wo, Wo_b, wn4);

  dim3 blk(256);
  gemm_bt<0, BQ><<<dim3(BB * BQ / 128, DM / 128), blk, 0, stream>>>(qin_b, Wq_b, qp, nullptr);
  gemm_bt<0, TT><<<dim3(BB * TT / 128, DM / 128), blk, 0, stream>>>(kvin_b, Wk_b, kp, nullptr);
  gemm_bt<0, TT><<<dim3(BB * TT / 128, DM / 128), blk, 0, stream>>>(kvin_b, Wv_b, vp, nullptr);

  attn_kern<<<dim3(BB * NH, BQ / 64), blk, 0, stream>>>(qp, kp, vp, ao);

  gemm_bt<1, BQ><<<dim3(BB * BQ / 128, DM / 128), blk, 0, stream>>>(ao, Wo_b, nullptr, out);
}

// Round 2
// 394.812 us; speedup vs baseline: 1.2210x; 1.2210x over previous
//
#include <hip/hip_runtime.h>
#include <hip/hip_bf16.h>
#include <cstdint>
#include <cstddef>

#define DM 1024
#define NH 16
#define DH 64
#define BQ 1024
#define TT 4096
#define BB 4

using f32x4 = __attribute__((ext_vector_type(4))) float;
using s16x8 = __attribute__((ext_vector_type(8))) short;

__device__ __forceinline__ unsigned short f2bf(float f) {
  union { float f; unsigned int u; } v; v.f = f;
  unsigned int u = v.u;
  unsigned int r = (u + 0x7FFFu + ((u >> 16) & 1u)) >> 16;
  return (unsigned short)r;
}

__global__ void cvt_f32_bf16(const float* __restrict__ in, unsigned short* __restrict__ out, int n4) {
  int i = blockIdx.x * blockDim.x + threadIdx.x;
  if (i < n4) {
    float4 v = reinterpret_cast<const float4*>(in)[i];
    ushort4 o;
    o.x = f2bf(v.x); o.y = f2bf(v.y); o.z = f2bf(v.z); o.w = f2bf(v.w);
    reinterpret_cast<ushort4*>(out)[i] = o;
  }
}

__device__ __forceinline__ void gload_lds16(const unsigned short* g, unsigned short* l) {
  __builtin_amdgcn_global_load_lds(
      (const __attribute__((address_space(1))) unsigned int*)g,
      (__attribute__((address_space(3))) unsigned int*)l,
      16, 0, 0);
}

// C[m,n] = sum_k A[m,k] * W[n,k]   (A: Mx1024 bf16, W: 1024x1024 bf16, row-major)
// MODE 0: write bf16 scattered to [B, NH, SEQ, DH];  MODE 1: write f32 row-major [M, 1024]
template<int MODE, int SEQ>
__global__ __launch_bounds__(256) void gemm_bt(const unsigned short* __restrict__ A,
                                               const unsigned short* __restrict__ W,
                                               unsigned short* __restrict__ Cb,
                                               float* __restrict__ Cf) {
  __shared__ unsigned short As[128 * 32];
  __shared__ unsigned short Bs[128 * 32];
  const int tid = threadIdx.x;
  const int wid = tid >> 6, lane = tid & 63;
  const int m0 = blockIdx.x * 128, n0 = blockIdx.y * 128;
  const int wr = wid >> 1, wc = wid & 1;
  const int fr = lane & 15;
  const int fk = (lane >> 4) * 8;

  f32x4 acc[4][4];
#pragma unroll
  for (int mt = 0; mt < 4; mt++)
#pragma unroll
    for (int nt = 0; nt < 4; nt++) acc[mt][nt] = f32x4{0.f, 0.f, 0.f, 0.f};

  const unsigned short* gA = A + (size_t)(m0 + wid * 32 + (lane >> 2)) * DM + (lane & 3) * 8;
  const unsigned short* gW = W + (size_t)(n0 + wid * 32 + (lane >> 2)) * DM + (lane & 3) * 8;
  unsigned short* lA0 = &As[(wid * 32) * 32];
  unsigned short* lA1 = &As[(wid * 32 + 16) * 32];
  unsigned short* lB0 = &Bs[(wid * 32) * 32];
  unsigned short* lB1 = &Bs[(wid * 32 + 16) * 32];

  for (int kt = 0; kt < DM / 32; ++kt) {
    gload_lds16(gA, lA0);
    gload_lds16(gA + 16 * DM, lA1);
    gload_lds16(gW, lB0);
    gload_lds16(gW + 16 * DM, lB1);
    gA += 32; gW += 32;
    __syncthreads();
    s16x8 af[4], bfv[4];
#pragma unroll
    for (int mt = 0; mt < 4; mt++)
      af[mt] = *reinterpret_cast<const s16x8*>(&As[(wr * 64 + mt * 16 + fr) * 32 + fk]);
#pragma unroll
    for (int nt = 0; nt < 4; nt++)
      bfv[nt] = *reinterpret_cast<const s16x8*>(&Bs[(wc * 64 + nt * 16 + fr) * 32 + fk]);
#pragma unroll
    for (int mt = 0; mt < 4; mt++)
#pragma unroll
      for (int nt = 0; nt < 4; nt++)
        acc[mt][nt] = __builtin_amdgcn_mfma_f32_16x16x32_bf16(af[mt], bfv[nt], acc[mt][nt], 0, 0, 0);
    __syncthreads();
  }

#pragma unroll
  for (int mt = 0; mt < 4; mt++) {
#pragma unroll
    for (int nt = 0; nt < 4; nt++) {
      const int col = n0 + wc * 64 + nt * 16 + fr;
#pragma unroll
      for (int r = 0; r < 4; r++) {
        const int m = m0 + wr * 64 + mt * 16 + (lane >> 4) * 4 + r;
        if constexpr (MODE == 0) {
          const int b = m / SEQ, sr = m % SEQ;
          const int h = col >> 6, dh = col & 63;
          Cb[((size_t)(b * NH + h) * SEQ + sr) * DH + dh] = f2bf(acc[mt][nt][r]);
        } else {
          Cf[(size_t)m * DM + col] = acc[mt][nt][r];
        }
      }
    }
  }
}

// Transpose V: [B,H,T,DH] -> [B,H,DH,T], 64x64 tiles through swizzled LDS.
__global__ __launch_bounds__(256) void transpose_v(const unsigned short* __restrict__ vp,
                                                   unsigned short* __restrict__ vt) {
  __shared__ unsigned short tile[64 * 64];
  const int bh = blockIdx.x;
  const int t0 = blockIdx.y * 64;
  const int tid = threadIdx.x;
  const int c8 = tid & 7;
  const int r0 = tid >> 3;  // 0..31
  const size_t ibase = ((size_t)bh * TT + t0) * DH;
#pragma unroll
  for (int s = 0; s < 2; s++) {
    const int t = r0 + s * 32;
    s16x8 v = *reinterpret_cast<const s16x8*>(&vp[ibase + (size_t)t * DH + c8 * 8]);
    *reinterpret_cast<s16x8*>(&tile[t * 64 + ((c8 ^ (t & 7) ^ (t >> 3)) * 8)]) = v;
  }
  __syncthreads();
  const size_t obase = (size_t)bh * DH * TT + t0;
#pragma unroll
  for (int s = 0; s < 2; s++) {
    const int d = r0 + s * 32;
    s16x8 o;
#pragma unroll
    for (int j = 0; j < 8; j++) {
      // element (t = c8*8+j, d): stored chunk position = (d>>3) ^ (t&7) ^ (t>>3)
      o[j] = (short)tile[(c8 * 8 + j) * 64 + (((d >> 3) ^ j ^ c8) * 8) + (d & 7)];
    }
    *reinterpret_cast<s16x8*>(&vt[obase + (size_t)d * TT + c8 * 8]) = o;
  }
}

// Flash attention: Qp/Kp are [B,NH,seq,DH] bf16; Vtg is [B,NH,DH,TT] bf16; Ob is [B,BQ,DM] bf16.
__global__ __launch_bounds__(256) void attn_kern(const unsigned short* __restrict__ Qp,
                                                 const unsigned short* __restrict__ Kp,
                                                 const unsigned short* __restrict__ Vtg,
                                                 unsigned short* __restrict__ Ob) {
  __shared__ unsigned short Ks[2][64 * 64];
  __shared__ unsigned short Vs[2][64 * 64];
  __shared__ unsigned short Ps[4][16 * 64];
  const int bh = blockIdx.x;  // b*NH + h
  const int b = bh >> 4, h = bh & 15;
  const int q0 = blockIdx.y * 64;
  const int tid = threadIdx.x, wid = tid >> 6, lane = tid & 63;
  const int fr = lane & 15;
  const int klg = lane >> 4;
  const int fk = klg * 8;

  const size_t qbase = ((size_t)bh * BQ + q0 + wid * 16 + fr) * DH;
  s16x8 qf[2];
  qf[0] = *reinterpret_cast<const s16x8*>(&Qp[qbase + fk]);
  qf[1] = *reinterpret_cast<const s16x8*>(&Qp[qbase + 32 + fk]);

  f32x4 o[4];
  float mrun[4], lrun[4];
#pragma unroll
  for (int i = 0; i < 4; i++) { o[i] = f32x4{0.f, 0.f, 0.f, 0.f}; mrun[i] = -1e30f; lrun[i] = 0.f; }

  const size_t kvbase = (size_t)bh * TT * DH;  // also = bh * DH * TT for Vtg
  const int srow = lane >> 3, c8 = lane & 7;

  auto stage = [&](int buf, int t0) {
#pragma unroll
    for (int s = 0; s < 2; s++) {
      const int rk = wid * 16 + s * 8 + srow;  // K row (t) / Vt row (d)
      // inverse-swizzled global source, linear LDS dest (base + lane*16B)
      gload_lds16(Kp + kvbase + (size_t)(t0 + rk) * DH + (c8 ^ (rk & 7)) * 8,
                  &Ks[buf][wid * 1024 + s * 512]);
      gload_lds16(Vtg + kvbase + (size_t)rk * TT + t0 + (c8 ^ (rk & 7)) * 8,
                  &Vs[buf][wid * 1024 + s * 512]);
    }
  };

  stage(0, 0);
  __syncthreads();

  for (int it = 0; it < TT / 64; ++it) {
    const int cur = it & 1;
    if (it + 1 < TT / 64) stage(cur ^ 1, (it + 1) * 64);  // prefetch overlaps compute

    // S = q @ k^T  (rows: q-local regs, cols: t-local = fr)
    f32x4 s4[4];
#pragma unroll
    for (int nt = 0; nt < 4; nt++) {
      s4[nt] = f32x4{0.f, 0.f, 0.f, 0.f};
      const int trow = nt * 16 + fr;
#pragma unroll
      for (int kc = 0; kc < 2; kc++) {
        s16x8 kb = *reinterpret_cast<const s16x8*>(
            &Ks[cur][trow * 64 + (((kc * 4 + klg) ^ (trow & 7)) * 8)]);
        s4[nt] = __builtin_amdgcn_mfma_f32_16x16x32_bf16(qf[kc], kb, s4[nt], 0, 0, 0);
      }
    }

    const float scale = 0.125f;  // 1/sqrt(64)
    float tm[4];
#pragma unroll
    for (int r = 0; r < 4; r++)
      tm[r] = fmaxf(fmaxf(s4[0][r], s4[1][r]), fmaxf(s4[2][r], s4[3][r])) * scale;
#pragma unroll
    for (int d = 1; d < 16; d <<= 1)
#pragma unroll
      for (int r = 0; r < 4; r++) tm[r] = fmaxf(tm[r], __shfl_xor(tm[r], d));

    float al[4], ls[4];
#pragma unroll
    for (int r = 0; r < 4; r++) {
      float mn = fmaxf(mrun[r], tm[r]);
      al[r] = __expf(mrun[r] - mn);
      mrun[r] = mn;
      ls[r] = 0.f;
    }
#pragma unroll
    for (int nt = 0; nt < 4; nt++) {
#pragma unroll
      for (int r = 0; r < 4; r++) {
        float p = __expf(s4[nt][r] * scale - mrun[r]);
        ls[r] += p;
        const int row = klg * 4 + r;
        const int col = nt * 16 + fr;
        Ps[wid][row * 64 + (col ^ ((row & 7) << 3))] = f2bf(p);
      }
    }
#pragma unroll
    for (int d = 1; d < 16; d <<= 1)
#pragma unroll
      for (int r = 0; r < 4; r++) ls[r] += __shfl_xor(ls[r], d);
#pragma unroll
    for (int r = 0; r < 4; r++) lrun[r] = lrun[r] * al[r] + ls[r];
#pragma unroll
    for (int nt = 0; nt < 4; nt++)
#pragma unroll
      for (int r = 0; r < 4; r++) o[nt][r] *= al[r];

    // O += P @ V   (B-operand from pre-transposed V tile)
    s16x8 pa[2];
#pragma unroll
    for (int kc = 0; kc < 2; kc++)
      pa[kc] = *reinterpret_cast<const s16x8*>(&Ps[wid][fr * 64 + ((kc * 32 + fk) ^ ((fr & 7) << 3))]);
#pragma unroll
    for (int nt = 0; nt < 4; nt++) {
      const int vrow = nt * 16 + fr;  // d index
#pragma unroll
      for (int kc = 0; kc < 2; kc++) {
        s16x8 vb = *reinterpret_cast<const s16x8*>(
            &Vs[cur][vrow * 64 + (((kc * 4 + klg) ^ (vrow & 7)) * 8)]);
        o[nt] = __builtin_amdgcn_mfma_f32_16x16x32_bf16(pa[kc], vb, o[nt], 0, 0, 0);
      }
    }

    __syncthreads();  // drains prefetch (vmcnt0) + WAR protection for buf swap
  }

#pragma unroll
  for (int nt = 0; nt < 4; nt++) {
#pragma unroll
    for (int r = 0; r < 4; r++) {
      const int qr = q0 + wid * 16 + klg * 4 + r;
      const int col = h * DH + nt * 16 + fr;
      Ob[((size_t)b * BQ + qr) * DM + col] = f2bf(o[nt][r] / lrun[r]);
    }
  }
}

extern "C" void kernel_launch(void* const* d_in, const int* in_sizes, int n_in,
                              void* d_out, int out_size, void* d_ws, size_t ws_size,
                              hipStream_t stream) {
  const float* q_in = (const float*)d_in[0];
  const float* kv_in = (const float*)d_in[1];
  const float* Wq = (const float*)d_in[2];
  const float* Wk = (const float*)d_in[3];
  const float* Wv = (const float*)d_in[4];
  const float* Wv2 = (const float*)d_in[4];
  const float* Wo = (const float*)d_in[5];
  float* out = (float*)d_out;

  char* ws = (char*)d_ws;
  unsigned short* qin_b = (unsigned short*)ws;  ws += (size_t)BB * BQ * DM * 2;
  unsigned short* kvin_b = (unsigned short*)ws; ws += (size_t)BB * TT * DM * 2;
  unsigned short* Wq_b = (unsigned short*)ws;   ws += (size_t)DM * DM * 2;
  unsigned short* Wk_b = (unsigned short*)ws;   ws += (size_t)DM * DM * 2;
  unsigned short* Wv_b = (unsigned short*)ws;   ws += (size_t)DM * DM * 2;
  unsigned short* Wo_b = (unsigned short*)ws;   ws += (size_t)DM * DM * 2;
  unsigned short* qp = (unsigned short*)ws;     ws += (size_t)BB * NH * BQ * DH * 2;
  unsigned short* kp = (unsigned short*)ws;     ws += (size_t)BB * NH * TT * DH * 2;
  unsigned short* vp = (unsigned short*)ws;     ws += (size_t)BB * NH * TT * DH * 2;
  unsigned short* ao = (unsigned short*)ws;     ws += (size_t)BB * BQ * DM * 2;
  // vt aliases kvin_b: kv_in bf16 is dead after the V projection GEMM.
  unsigned short* vt = kvin_b;

  const int qn4 = BB * BQ * DM / 4;
  const int kvn4 = BB * TT * DM / 4;
  const int wn4 = DM * DM / 4;
  cvt_f32_bf16<<<(qn4 + 255) / 256, 256, 0, stream>>>(q_in, qin_b, qn4);
  cvt_f32_bf16<<<(kvn4 + 255) / 256, 256, 0, stream>>>(kv_in, kvin_b, kvn4);
  cvt_f32_bf16<<<(wn4 + 255) / 256, 256, 0, stream>>>(Wq, Wq_b, wn4);
  cvt_f32_bf16<<<(wn4 + 255) / 256, 256, 0, stream>>>(Wk, Wk_b, wn4);
  cvt_f32_bf16<<<(wn4 + 255) / 256, 256, 0, stream>>>(Wv, Wv_b, wn4);
  cvt_f32_bf16<<<(wn4 + 255) / 256, 256, 0, stream>>>(Wo, Wo_b, wn4);

  dim3 blk(256);
  gemm_bt<0, BQ><<<dim3(BB * BQ / 128, DM / 128), blk, 0, stream>>>(qin_b, Wq_b, qp, nullptr);
  gemm_bt<0, TT><<<dim3(BB * TT / 128, DM / 128), blk, 0, stream>>>(kvin_b, Wk_b, kp, nullptr);
  gemm_bt<0, TT><<<dim3(BB * TT / 128, DM / 128), blk, 0, stream>>>(kvin_b, Wv_b, vp, nullptr);

  transpose_v<<<dim3(BB * NH, TT / 64), blk, 0, stream>>>(vp, vt);

  attn_kern<<<dim3(BB * NH, BQ / 64), blk, 0, stream>>>(qp, kp, vt, ao);

  gemm_bt<1, BQ><<<dim3(BB * BQ / 128, DM / 128), blk, 0, stream>>>(ao, Wo_b, nullptr, out);
}

// Round 3
// 371.544 us; speedup vs baseline: 1.2975x; 1.0626x over previous
//
#include <hip/hip_runtime.h>
#include <hip/hip_bf16.h>
#include <cstdint>
#include <cstddef>

#define DM 1024
#define NH 16
#define DH 64
#define BQ 1024
#define TT 4096
#define BB 4

using f32x4 = __attribute__((ext_vector_type(4))) float;
using s16x8 = __attribute__((ext_vector_type(8))) short;

// native f32 -> bf16 (RNE via HW cvt; compiler picks v_cvt / cvt_pk forms)
__device__ __forceinline__ unsigned short f2bf(float f) {
  union { __hip_bfloat16 h; unsigned short u; } c;
  c.h = __float2bfloat16(f);
  return c.u;
}

__global__ void cvt_f32_bf16(const float* __restrict__ in, unsigned short* __restrict__ out, int n4) {
  int i = blockIdx.x * blockDim.x + threadIdx.x;
  if (i < n4) {
    float4 v = reinterpret_cast<const float4*>(in)[i];
    ushort4 o;
    o.x = f2bf(v.x); o.y = f2bf(v.y); o.z = f2bf(v.z); o.w = f2bf(v.w);
    reinterpret_cast<ushort4*>(out)[i] = o;
  }
}

__device__ __forceinline__ void gload_lds16(const unsigned short* g, unsigned short* l) {
  __builtin_amdgcn_global_load_lds(
      (const __attribute__((address_space(1))) unsigned int*)g,
      (__attribute__((address_space(3))) unsigned int*)l,
      16, 0, 0);
}

// C[m,n] = sum_k A[m,k] * W[n,k]   (A: Mx1024 bf16, W: 1024x1024 bf16, row-major)
// MODE 0: write bf16 scattered to [B, NH, SEQ, DH] (opt. pre-scaled); MODE 1: f32 [M, 1024]
template<int MODE, int SEQ, bool PRESCALE>
__global__ __launch_bounds__(256) void gemm_bt(const unsigned short* __restrict__ A,
                                               const unsigned short* __restrict__ W,
                                               unsigned short* __restrict__ Cb,
                                               float* __restrict__ Cf) {
  __shared__ unsigned short As[128 * 32];
  __shared__ unsigned short Bs[128 * 32];
  const int tid = threadIdx.x;
  const int wid = tid >> 6, lane = tid & 63;
  const int m0 = blockIdx.x * 128, n0 = blockIdx.y * 128;
  const int wr = wid >> 1, wc = wid & 1;
  const int fr = lane & 15;
  const int fk = (lane >> 4) * 8;

  f32x4 acc[4][4];
#pragma unroll
  for (int mt = 0; mt < 4; mt++)
#pragma unroll
    for (int nt = 0; nt < 4; nt++) acc[mt][nt] = f32x4{0.f, 0.f, 0.f, 0.f};

  const unsigned short* gA = A + (size_t)(m0 + wid * 32 + (lane >> 2)) * DM + (lane & 3) * 8;
  const unsigned short* gW = W + (size_t)(n0 + wid * 32 + (lane >> 2)) * DM + (lane & 3) * 8;
  unsigned short* lA0 = &As[(wid * 32) * 32];
  unsigned short* lA1 = &As[(wid * 32 + 16) * 32];
  unsigned short* lB0 = &Bs[(wid * 32) * 32];
  unsigned short* lB1 = &Bs[(wid * 32 + 16) * 32];

  for (int kt = 0; kt < DM / 32; ++kt) {
    gload_lds16(gA, lA0);
    gload_lds16(gA + 16 * DM, lA1);
    gload_lds16(gW, lB0);
    gload_lds16(gW + 16 * DM, lB1);
    gA += 32; gW += 32;
    __syncthreads();
    s16x8 af[4], bfv[4];
#pragma unroll
    for (int mt = 0; mt < 4; mt++)
      af[mt] = *reinterpret_cast<const s16x8*>(&As[(wr * 64 + mt * 16 + fr) * 32 + fk]);
#pragma unroll
    for (int nt = 0; nt < 4; nt++)
      bfv[nt] = *reinterpret_cast<const s16x8*>(&Bs[(wc * 64 + nt * 16 + fr) * 32 + fk]);
    __builtin_amdgcn_s_setprio(1);
#pragma unroll
    for (int mt = 0; mt < 4; mt++)
#pragma unroll
      for (int nt = 0; nt < 4; nt++)
        acc[mt][nt] = __builtin_amdgcn_mfma_f32_16x16x32_bf16(af[mt], bfv[nt], acc[mt][nt], 0, 0, 0);
    __builtin_amdgcn_s_setprio(0);
    __syncthreads();
  }

#pragma unroll
  for (int mt = 0; mt < 4; mt++) {
#pragma unroll
    for (int nt = 0; nt < 4; nt++) {
      const int col = n0 + wc * 64 + nt * 16 + fr;
#pragma unroll
      for (int r = 0; r < 4; r++) {
        const int m = m0 + wr * 64 + mt * 16 + (lane >> 4) * 4 + r;
        float v = acc[mt][nt][r];
        if constexpr (PRESCALE) v *= 0.18033688011112042f;  // 0.125 * log2(e)
        if constexpr (MODE == 0) {
          const int b = m / SEQ, sr = m % SEQ;
          const int h = col >> 6, dh = col & 63;
          Cb[((size_t)(b * NH + h) * SEQ + sr) * DH + dh] = f2bf(v);
        } else {
          Cf[(size_t)m * DM + col] = v;
        }
      }
    }
  }
}

// Transpose V: [B,H,T,DH] -> [B,H,DH,T], 64x64 tiles through swizzled LDS.
__global__ __launch_bounds__(256) void transpose_v(const unsigned short* __restrict__ vp,
                                                   unsigned short* __restrict__ vt) {
  __shared__ unsigned short tile[64 * 64];
  const int bh = blockIdx.x;
  const int t0 = blockIdx.y * 64;
  const int tid = threadIdx.x;
  const int c8 = tid & 7;
  const int r0 = tid >> 3;  // 0..31
  const size_t ibase = ((size_t)bh * TT + t0) * DH;
#pragma unroll
  for (int s = 0; s < 2; s++) {
    const int t = r0 + s * 32;
    s16x8 v = *reinterpret_cast<const s16x8*>(&vp[ibase + (size_t)t * DH + c8 * 8]);
    *reinterpret_cast<s16x8*>(&tile[t * 64 + ((c8 ^ (t & 7) ^ (t >> 3)) * 8)]) = v;
  }
  __syncthreads();
  const size_t obase = (size_t)bh * DH * TT + t0;
#pragma unroll
  for (int s = 0; s < 2; s++) {
    const int d = r0 + s * 32;
    s16x8 o;
#pragma unroll
    for (int j = 0; j < 8; j++) {
      o[j] = (short)tile[(c8 * 8 + j) * 64 + (((d >> 3) ^ j ^ c8) * 8) + (d & 7)];
    }
    *reinterpret_cast<s16x8*>(&vt[obase + (size_t)d * TT + c8 * 8]) = o;
  }
}

// Flash attention: Qp (pre-scaled by 0.125*log2e) / Kp are [B,NH,seq,DH] bf16;
// Vtg is [B,NH,DH,TT] bf16; Ob is [B,BQ,DM] bf16. Softmax in log2 domain.
__global__ __launch_bounds__(256) void attn_kern(const unsigned short* __restrict__ Qp,
                                                 const unsigned short* __restrict__ Kp,
                                                 const unsigned short* __restrict__ Vtg,
                                                 unsigned short* __restrict__ Ob) {
  __shared__ unsigned short Ks[2][64 * 64];
  __shared__ unsigned short Vs[2][64 * 64];
  __shared__ unsigned short Ps[4][16 * 64];
  const int bh = blockIdx.x;  // b*NH + h
  const int b = bh >> 4, h = bh & 15;
  const int q0 = blockIdx.y * 64;
  const int tid = threadIdx.x, wid = tid >> 6, lane = tid & 63;
  const int fr = lane & 15;
  const int klg = lane >> 4;
  const int fk = klg * 8;

  const size_t qbase = ((size_t)bh * BQ + q0 + wid * 16 + fr) * DH;
  s16x8 qf[2];
  qf[0] = *reinterpret_cast<const s16x8*>(&Qp[qbase + fk]);
  qf[1] = *reinterpret_cast<const s16x8*>(&Qp[qbase + 32 + fk]);

  f32x4 o[4];
  float mrun[4], lsum[4];
#pragma unroll
  for (int i = 0; i < 4; i++) { o[i] = f32x4{0.f, 0.f, 0.f, 0.f}; mrun[i] = -1e30f; lsum[i] = 0.f; }

  const size_t kvbase = (size_t)bh * TT * DH;  // also = bh * DH * TT for Vtg
  const int srow = lane >> 3, c8 = lane & 7;

  auto stage = [&](int buf, int t0) {
#pragma unroll
    for (int s = 0; s < 2; s++) {
      const int rk = wid * 16 + s * 8 + srow;  // K row (t) / Vt row (d)
      gload_lds16(Kp + kvbase + (size_t)(t0 + rk) * DH + (c8 ^ (rk & 7)) * 8,
                  &Ks[buf][wid * 1024 + s * 512]);
      gload_lds16(Vtg + kvbase + (size_t)rk * TT + t0 + (c8 ^ (rk & 7)) * 8,
                  &Vs[buf][wid * 1024 + s * 512]);
    }
  };

  stage(0, 0);
  __syncthreads();

  for (int it = 0; it < TT / 64; ++it) {
    const int cur = it & 1;
    if (it + 1 < TT / 64) stage(cur ^ 1, (it + 1) * 64);  // prefetch overlaps compute

    // S = q @ k^T in log2 domain (rows: q-local regs, cols: t-local = fr)
    f32x4 s4[4];
#pragma unroll
    for (int nt = 0; nt < 4; nt++) s4[nt] = f32x4{0.f, 0.f, 0.f, 0.f};
    __builtin_amdgcn_s_setprio(1);
#pragma unroll
    for (int nt = 0; nt < 4; nt++) {
      const int trow = nt * 16 + fr;
#pragma unroll
      for (int kc = 0; kc < 2; kc++) {
        s16x8 kb = *reinterpret_cast<const s16x8*>(
            &Ks[cur][trow * 64 + (((kc * 4 + klg) ^ (trow & 7)) * 8)]);
        s4[nt] = __builtin_amdgcn_mfma_f32_16x16x32_bf16(qf[kc], kb, s4[nt], 0, 0, 0);
      }
    }
    __builtin_amdgcn_s_setprio(0);

    // tile max per q-row (row-uniform across the 16-lane group after reduce)
    float tm[4];
#pragma unroll
    for (int r = 0; r < 4; r++)
      tm[r] = fmaxf(fmaxf(s4[0][r], s4[1][r]), fmaxf(s4[2][r], s4[3][r]));
#pragma unroll
    for (int d = 1; d < 16; d <<= 1)
#pragma unroll
      for (int r = 0; r < 4; r++) tm[r] = fmaxf(tm[r], __shfl_xor(tm[r], d));

    // defer-max (T13): only rescale when some row's max grew past threshold
    const bool need = !((tm[0] - mrun[0] <= 8.f) & (tm[1] - mrun[1] <= 8.f) &
                       (tm[2] - mrun[2] <= 8.f) & (tm[3] - mrun[3] <= 8.f));
    if (__any(need)) {
#pragma unroll
      for (int r = 0; r < 4; r++) {
        float mn = fmaxf(mrun[r], tm[r]);
        float al = exp2f(mrun[r] - mn);
        mrun[r] = mn;
        lsum[r] *= al;
#pragma unroll
        for (int nt = 0; nt < 4; nt++) o[nt][r] *= al;
      }
    }

    // P = exp2(S - m); lane-partial lsum (cross-lane reduce deferred to end)
#pragma unroll
    for (int nt = 0; nt < 4; nt++) {
#pragma unroll
      for (int r = 0; r < 4; r++) {
        float p = exp2f(s4[nt][r] - mrun[r]);
        lsum[r] += p;
        const int row = klg * 4 + r;
        const int col = nt * 16 + fr;
        Ps[wid][row * 64 + (col ^ ((row & 7) << 3))] = f2bf(p);
      }
    }

    // O += P @ V   (B-operand from pre-transposed V tile)
    s16x8 pa[2];
#pragma unroll
    for (int kc = 0; kc < 2; kc++)
      pa[kc] = *reinterpret_cast<const s16x8*>(&Ps[wid][fr * 64 + ((kc * 32 + fk) ^ ((fr & 7) << 3))]);
    __builtin_amdgcn_s_setprio(1);
#pragma unroll
    for (int nt = 0; nt < 4; nt++) {
      const int vrow = nt * 16 + fr;  // d index
#pragma unroll
      for (int kc = 0; kc < 2; kc++) {
        s16x8 vb = *reinterpret_cast<const s16x8*>(
            &Vs[cur][vrow * 64 + (((kc * 4 + klg) ^ (vrow & 7)) * 8)]);
        o[nt] = __builtin_amdgcn_mfma_f32_16x16x32_bf16(pa[kc], vb, o[nt], 0, 0, 0);
      }
    }
    __builtin_amdgcn_s_setprio(0);

    __syncthreads();  // drains prefetch + WAR protection for buf swap
  }

  // final cross-lane sum of lane-partial lsum (one reduce for the whole kernel)
#pragma unroll
  for (int d = 1; d < 16; d <<= 1)
#pragma unroll
    for (int r = 0; r < 4; r++) lsum[r] += __shfl_xor(lsum[r], d);

#pragma unroll
  for (int nt = 0; nt < 4; nt++) {
#pragma unroll
    for (int r = 0; r < 4; r++) {
      const int qr = q0 + wid * 16 + klg * 4 + r;
      const int col = h * DH + nt * 16 + fr;
      Ob[((size_t)b * BQ + qr) * DM + col] = f2bf(o[nt][r] / lsum[r]);
    }
  }
}

extern "C" void kernel_launch(void* const* d_in, const int* in_sizes, int n_in,
                              void* d_out, int out_size, void* d_ws, size_t ws_size,
                              hipStream_t stream) {
  const float* q_in = (const float*)d_in[0];
  const float* kv_in = (const float*)d_in[1];
  const float* Wq = (const float*)d_in[2];
  const float* Wk = (const float*)d_in[3];
  const float* Wv = (const float*)d_in[4];
  const float* Wo = (const float*)d_in[5];
  float* out = (float*)d_out;

  char* ws = (char*)d_ws;
  unsigned short* qin_b = (unsigned short*)ws;  ws += (size_t)BB * BQ * DM * 2;
  unsigned short* kvin_b = (unsigned short*)ws; ws += (size_t)BB * TT * DM * 2;
  unsigned short* Wq_b = (unsigned short*)ws;   ws += (size_t)DM * DM * 2;
  unsigned short* Wk_b = (unsigned short*)ws;   ws += (size_t)DM * DM * 2;
  unsigned short* Wv_b = (unsigned short*)ws;   ws += (size_t)DM * DM * 2;
  unsigned short* Wo_b = (unsigned short*)ws;   ws += (size_t)DM * DM * 2;
  unsigned short* qp = (unsigned short*)ws;     ws += (size_t)BB * NH * BQ * DH * 2;
  unsigned short* kp = (unsigned short*)ws;     ws += (size_t)BB * NH * TT * DH * 2;
  unsigned short* vp = (unsigned short*)ws;     ws += (size_t)BB * NH * TT * DH * 2;
  unsigned short* ao = (unsigned short*)ws;     ws += (size_t)BB * BQ * DM * 2;
  // vt aliases kvin_b: kv_in bf16 is dead after the V projection GEMM.
  unsigned short* vt = kvin_b;

  const int qn4 = BB * BQ * DM / 4;
  const int kvn4 = BB * TT * DM / 4;
  const int wn4 = DM * DM / 4;
  cvt_f32_bf16<<<(qn4 + 255) / 256, 256, 0, stream>>>(q_in, qin_b, qn4);
  cvt_f32_bf16<<<(kvn4 + 255) / 256, 256, 0, stream>>>(kv_in, kvin_b, kvn4);
  cvt_f32_bf16<<<(wn4 + 255) / 256, 256, 0, stream>>>(Wq, Wq_b, wn4);
  cvt_f32_bf16<<<(wn4 + 255) / 256, 256, 0, stream>>>(Wk, Wk_b, wn4);
  cvt_f32_bf16<<<(wn4 + 255) / 256, 256, 0, stream>>>(Wv, Wv_b, wn4);
  cvt_f32_bf16<<<(wn4 + 255) / 256, 256, 0, stream>>>(Wo, Wo_b, wn4);

  dim3 blk(256);
  gemm_bt<0, BQ, true><<<dim3(BB * BQ / 128, DM / 128), blk, 0, stream>>>(qin_b, Wq_b, qp, nullptr);
  gemm_bt<0, TT, false><<<dim3(BB * TT / 128, DM / 128), blk, 0, stream>>>(kvin_b, Wk_b, kp, nullptr);
  gemm_bt<0, TT, false><<<dim3(BB * TT / 128, DM / 128), blk, 0, stream>>>(kvin_b, Wv_b, vp, nullptr);

  transpose_v<<<dim3(BB * NH, TT / 64), blk, 0, stream>>>(vp, vt);

  attn_kern<<<dim3(BB * NH, BQ / 64), blk, 0, stream>>>(qp, kp, vt, ao);

  gemm_bt<1, BQ, false><<<dim3(BB * BQ / 128, DM / 128), blk, 0, stream>>>(ao, Wo_b, nullptr, out);
}

// Round 6
// 341.869 us; speedup vs baseline: 1.4101x; 1.0868x over previous
//
#include <hip/hip_runtime.h>
#include <hip/hip_bf16.h>
#include <cstdint>
#include <cstddef>

#define DM 1024
#define NH 16
#define DH 64
#define BQ 1024
#define TT 4096
#define BB 4

using f32x4 = __attribute__((ext_vector_type(4))) float;
using f32x16 = __attribute__((ext_vector_type(16))) float;
using s16x8 = __attribute__((ext_vector_type(8))) short;

// native f32 -> bf16 (RNE via HW cvt)
__device__ __forceinline__ unsigned short f2bf(float f) {
  union { __hip_bfloat16 h; unsigned short u; } c;
  c.h = __float2bfloat16(f);
  return c.u;
}

__device__ __forceinline__ f32x16 zero16() {
  f32x16 z;
#pragma unroll
  for (int i = 0; i < 16; i++) z[i] = 0.f;
  return z;
}

// pack two f32 -> one u32 of 2 bf16 (lo in [15:0], hi in [31:16]) — no asm
__device__ __forceinline__ int pack2(float lo, float hi2) {
  return (int)((unsigned int)f2bf(lo) | ((unsigned int)f2bf(hi2) << 16));
}

// Build PV A-operand fragment (8 bf16: t = 16kk+8hi+j) from lane-local P regs.
// p[r] = P[q=lane&31][t = 32g + (r&3)+8*(r>>2)+4*hi]; RB=0 -> low 16 t's, RB=8 -> high.
// Partner exchange via __shfl_xor(...,32) — no permlane asm (hazard-free).
template<int RB>
__device__ __forceinline__ s16x8 mkfrag(const f32x16& p, int hi) {
  const int W1 = pack2(p[RB + 0], p[RB + 1]);  // hi=0:(t0,t1)   hi=1:(t4,t5)
  const int W3 = pack2(p[RB + 2], p[RB + 3]);  // hi=0:(t2,t3)   hi=1:(t6,t7)
  const int W2 = pack2(p[RB + 4], p[RB + 5]);  // hi=0:(t8,t9)   hi=1:(t12,t13)
  const int W4 = pack2(p[RB + 6], p[RB + 7]);  // hi=0:(t10,t11) hi=1:(t14,t15)
  const int s1 = __shfl_xor(W1, 32);
  const int s3 = __shfl_xor(W3, 32);
  const int s2 = __shfl_xor(W2, 32);
  const int s4 = __shfl_xor(W4, 32);
  union { int i[4]; s16x8 v; } u;
  u.i[0] = hi ? s2 : W1;  // t = 8hi+0,1
  u.i[1] = hi ? s4 : W3;  // t = 8hi+2,3
  u.i[2] = hi ? W2 : s1;  // t = 8hi+4,5
  u.i[3] = hi ? W4 : s3;  // t = 8hi+6,7
  return u.v;
}

__global__ void cvt_f32_bf16(const float* __restrict__ in, unsigned short* __restrict__ out, int n4) {
  int i = blockIdx.x * blockDim.x + threadIdx.x;
  if (i < n4) {
    float4 v = reinterpret_cast<const float4*>(in)[i];
    ushort4 o;
    o.x = f2bf(v.x); o.y = f2bf(v.y); o.z = f2bf(v.z); o.w = f2bf(v.w);
    reinterpret_cast<ushort4*>(out)[i] = o;
  }
}

__device__ __forceinline__ void gload_lds16(const unsigned short* g, unsigned short* l) {
  __builtin_amdgcn_global_load_lds(
      (const __attribute__((address_space(1))) unsigned int*)g,
      (__attribute__((address_space(3))) unsigned int*)l,
      16, 0, 0);
}

// C[m,n] = sum_k A[m,k] * W[n,k]   (A: Mx1024 bf16, W: 1024x1024 bf16, row-major)
// MODE 0: write bf16 scattered to [B, NH, SEQ, DH] (opt. pre-scaled); MODE 1: f32 [M, 1024]
template<int MODE, int SEQ, bool PRESCALE>
__global__ __launch_bounds__(256) void gemm_bt(const unsigned short* __restrict__ A,
                                               const unsigned short* __restrict__ W,
                                               unsigned short* __restrict__ Cb,
                                               float* __restrict__ Cf) {
  __shared__ unsigned short As[128 * 32];
  __shared__ unsigned short Bs[128 * 32];
  const int tid = threadIdx.x;
  const int wid = tid >> 6, lane = tid & 63;
  const int m0 = blockIdx.x * 128, n0 = blockIdx.y * 128;
  const int wr = wid >> 1, wc = wid & 1;
  const int fr = lane & 15;
  const int fk = (lane >> 4) * 8;

  f32x4 acc[4][4];
#pragma unroll
  for (int mt = 0; mt < 4; mt++)
#pragma unroll
    for (int nt = 0; nt < 4; nt++) acc[mt][nt] = f32x4{0.f, 0.f, 0.f, 0.f};

  const unsigned short* gA = A + (size_t)(m0 + wid * 32 + (lane >> 2)) * DM + (lane & 3) * 8;
  const unsigned short* gW = W + (size_t)(n0 + wid * 32 + (lane >> 2)) * DM + (lane & 3) * 8;
  unsigned short* lA0 = &As[(wid * 32) * 32];
  unsigned short* lA1 = &As[(wid * 32 + 16) * 32];
  unsigned short* lB0 = &Bs[(wid * 32) * 32];
  unsigned short* lB1 = &Bs[(wid * 32 + 16) * 32];

  for (int kt = 0; kt < DM / 32; ++kt) {
    gload_lds16(gA, lA0);
    gload_lds16(gA + 16 * DM, lA1);
    gload_lds16(gW, lB0);
    gload_lds16(gW + 16 * DM, lB1);
    gA += 32; gW += 32;
    __syncthreads();
    s16x8 af[4], bfv[4];
#pragma unroll
    for (int mt = 0; mt < 4; mt++)
      af[mt] = *reinterpret_cast<const s16x8*>(&As[(wr * 64 + mt * 16 + fr) * 32 + fk]);
#pragma unroll
    for (int nt = 0; nt < 4; nt++)
      bfv[nt] = *reinterpret_cast<const s16x8*>(&Bs[(wc * 64 + nt * 16 + fr) * 32 + fk]);
    __builtin_amdgcn_s_setprio(1);
#pragma unroll
    for (int mt = 0; mt < 4; mt++)
#pragma unroll
      for (int nt = 0; nt < 4; nt++)
        acc[mt][nt] = __builtin_amdgcn_mfma_f32_16x16x32_bf16(af[mt], bfv[nt], acc[mt][nt], 0, 0, 0);
    __builtin_amdgcn_s_setprio(0);
    __syncthreads();
  }

#pragma unroll
  for (int mt = 0; mt < 4; mt++) {
#pragma unroll
    for (int nt = 0; nt < 4; nt++) {
      const int col = n0 + wc * 64 + nt * 16 + fr;
#pragma unroll
      for (int r = 0; r < 4; r++) {
        const int m = m0 + wr * 64 + mt * 16 + (lane >> 4) * 4 + r;
        float v = acc[mt][nt][r];
        if constexpr (PRESCALE) v *= 0.18033688011112042f;  // 0.125 * log2(e)
        if constexpr (MODE == 0) {
          const int b = m / SEQ, sr = m % SEQ;
          const int h = col >> 6, dh = col & 63;
          Cb[((size_t)(b * NH + h) * SEQ + sr) * DH + dh] = f2bf(v);
        } else {
          Cf[(size_t)m * DM + col] = v;
        }
      }
    }
  }
}

// Transpose V: [B,H,T,DH] -> [B,H,DH,T], 64x64 tiles through swizzled LDS.
__global__ __launch_bounds__(256) void transpose_v(const unsigned short* __restrict__ vp,
                                                   unsigned short* __restrict__ vt) {
  __shared__ unsigned short tile[64 * 64];
  const int bh = blockIdx.x;
  const int t0 = blockIdx.y * 64;
  const int tid = threadIdx.x;
  const int c8 = tid & 7;
  const int r0 = tid >> 3;  // 0..31
  const size_t ibase = ((size_t)bh * TT + t0) * DH;
#pragma unroll
  for (int s = 0; s < 2; s++) {
    const int t = r0 + s * 32;
    s16x8 v = *reinterpret_cast<const s16x8*>(&vp[ibase + (size_t)t * DH + c8 * 8]);
    *reinterpret_cast<s16x8*>(&tile[t * 64 + ((c8 ^ (t & 7) ^ (t >> 3)) * 8)]) = v;
  }
  __syncthreads();
  const size_t obase = (size_t)bh * DH * TT + t0;
#pragma unroll
  for (int s = 0; s < 2; s++) {
    const int d = r0 + s * 32;
    s16x8 o;
#pragma unroll
    for (int j = 0; j < 8; j++) {
      o[j] = (short)tile[(c8 * 8 + j) * 64 + (((d >> 3) ^ j ^ c8) * 8) + (d & 7)];
    }
    *reinterpret_cast<s16x8*>(&vt[obase + (size_t)d * TT + c8 * 8]) = o;
  }
}

// Flash attention, m214-style: 4 warps x 32 q-rows, 32x32x16 MFMA, swapped QK^T,
// in-register softmax (log2 domain; Qp pre-scaled by 0.125*log2e).
// Qp/Kp: [B,NH,seq,DH] bf16; Vtg: [B,NH,DH,TT] bf16; Ob: [B,BQ,DM] bf16.
__global__ __launch_bounds__(256) void attn_kern(const unsigned short* __restrict__ Qp,
                                                 const unsigned short* __restrict__ Kp,
                                                 const unsigned short* __restrict__ Vtg,
                                                 unsigned short* __restrict__ Ob) {
  __shared__ unsigned short Ks[2][64 * 64];
  __shared__ unsigned short Vs[2][64 * 64];
  __shared__ float als[4][32];
  const int bh = blockIdx.x;  // b*NH + h
  const int b = bh >> 4, h = bh & 15;
  const int q0 = blockIdx.y * 128;
  const int tid = threadIdx.x, wid = tid >> 6, lane = tid & 63;
  const int l31 = lane & 31, hi = lane >> 5;

  // Q fragment (B-operand of swapped QK^T): lane holds Q[q=l31][dh=16kk+8hi+j]
  const size_t qrow = (size_t)bh * BQ + q0 + wid * 32 + l31;
  s16x8 qf[4];
#pragma unroll
  for (int kk = 0; kk < 4; kk++)
    qf[kk] = *reinterpret_cast<const s16x8*>(&Qp[qrow * DH + 16 * kk + 8 * hi]);

  f32x16 o0 = zero16(), o1 = zero16();
  float mrun = -3e38f, lsum = 0.f;

  const size_t kvbase = (size_t)bh * TT * DH;  // also = bh * DH * TT for Vtg
  const int srow = lane >> 3, c8 = lane & 7;

  auto stage = [&](int buf, int t0) {
#pragma unroll
    for (int s = 0; s < 2; s++) {
      const int rk = wid * 16 + s * 8 + srow;  // K row (t) / Vt row (d)
      gload_lds16(Kp + kvbase + (size_t)(t0 + rk) * DH + (c8 ^ (rk & 7)) * 8,
                  &Ks[buf][wid * 1024 + s * 512]);
      gload_lds16(Vtg + kvbase + (size_t)rk * TT + t0 + (c8 ^ (rk & 7)) * 8,
                  &Vs[buf][wid * 1024 + s * 512]);
    }
  };

  stage(0, 0);
  __syncthreads();

  const int rowA = l31;            // t/d row for group 0
  const int rowB = 32 + l31;       // group 1 (same &7 swizzle key)
  const int sw = l31 & 7;

  for (int it = 0; it < TT / 64; ++it) {
    const int cur = it & 1;
    if (it + 1 < TT / 64) stage(cur ^ 1, (it + 1) * 64);  // prefetch overlaps compute

    // S^T = K @ Q^T : D[t][q], col=lane&31=q, row t=crow(r,hi)
    f32x16 s0 = zero16(), s1 = zero16();
    __builtin_amdgcn_s_setprio(1);
#pragma unroll
    for (int kk = 0; kk < 4; kk++) {
      s16x8 kb0 = *reinterpret_cast<const s16x8*>(&Ks[cur][rowA * 64 + (((2 * kk + hi) ^ sw) * 8)]);
      s0 = __builtin_amdgcn_mfma_f32_32x32x16_bf16(kb0, qf[kk], s0, 0, 0, 0);
      s16x8 kb1 = *reinterpret_cast<const s16x8*>(&Ks[cur][rowB * 64 + (((2 * kk + hi) ^ sw) * 8)]);
      s1 = __builtin_amdgcn_mfma_f32_32x32x16_bf16(kb1, qf[kk], s1, 0, 0, 0);
    }
    __builtin_amdgcn_s_setprio(0);

    // in-lane tile max over this lane's 32 P-candidates, then partner combine
    // (lanes l / l+32 hold the same q with disjoint t-halves)
    float tm = fmaxf(s0[0], s1[0]);
#pragma unroll
    for (int r = 1; r < 16; r++) tm = fmaxf(tm, fmaxf(s0[r], s1[r]));
    tm = fmaxf(tm, __shfl_xor(tm, 32));

    // defer-max (T13, log2 domain, THR=8)
    if (__any(tm - mrun > 8.f)) {
      const float mn = fmaxf(mrun, tm);
      const float al = exp2f(mrun - mn);
      mrun = mn;
      lsum *= al;
      if (lane < 32) als[wid][lane] = al;   // al indexed by q
#pragma unroll
      for (int r = 0; r < 16; r++) {
        const float av = als[wid][(r & 3) + 8 * (r >> 2) + 4 * hi];
        o0[r] *= av; o1[r] *= av;
      }
    }

    // P = exp2(S - m), lane-local; lsum stays lane-partial (partner-combined at end)
#pragma unroll
    for (int r = 0; r < 16; r++) {
      s0[r] = exp2f(s0[r] - mrun); lsum += s0[r];
      s1[r] = exp2f(s1[r] - mrun); lsum += s1[r];
    }

    // in-register P -> PV A-operand (pack + shfl_xor partner exchange, no asm)
    s16x8 pa[4];
    pa[0] = mkfrag<0>(s0, hi);
    pa[1] = mkfrag<8>(s0, hi);
    pa[2] = mkfrag<0>(s1, hi);
    pa[3] = mkfrag<8>(s1, hi);

    // O += P @ V : B-operand from V^T tile rows (d), D[q][d] col=lane&31=d
    __builtin_amdgcn_s_setprio(1);
#pragma unroll
    for (int kk = 0; kk < 4; kk++) {
      s16x8 vb0 = *reinterpret_cast<const s16x8*>(&Vs[cur][rowA * 64 + (((2 * kk + hi) ^ sw) * 8)]);
      o0 = __builtin_amdgcn_mfma_f32_32x32x16_bf16(pa[kk], vb0, o0, 0, 0, 0);
      s16x8 vb1 = *reinterpret_cast<const s16x8*>(&Vs[cur][rowB * 64 + (((2 * kk + hi) ^ sw) * 8)]);
      o1 = __builtin_amdgcn_mfma_f32_32x32x16_bf16(pa[kk], vb1, o1, 0, 0, 0);
    }
    __builtin_amdgcn_s_setprio(0);

    __syncthreads();  // drains prefetch + WAR protection for buf swap
  }

  // combine partner lsum halves (lanes l / l+32 hold same q, disjoint t)
  lsum += __shfl_xor(lsum, 32);
  if (lane < 32) als[wid][lane] = lsum;

#pragma unroll
  for (int r = 0; r < 16; r++) {
    const int q = (r & 3) + 8 * (r >> 2) + 4 * hi;
    const float inv = 1.0f / als[wid][q];
    const size_t orow = ((size_t)b * BQ + q0 + wid * 32 + q) * DM + h * DH;
    Ob[orow + l31] = f2bf(o0[r] * inv);
    Ob[orow + 32 + l31] = f2bf(o1[r] * inv);
  }
}

extern "C" void kernel_launch(void* const* d_in, const int* in_sizes, int n_in,
                              void* d_out, int out_size, void* d_ws, size_t ws_size,
                              hipStream_t stream) {
  const float* q_in = (const float*)d_in[0];
  const float* kv_in = (const float*)d_in[1];
  const float* Wq = (const float*)d_in[2];
  const float* Wk = (const float*)d_in[3];
  const float* Wv = (const float*)d_in[4];
  const float* Wo = (const float*)d_in[5];
  float* out = (float*)d_out;

  char* ws = (char*)d_ws;
  unsigned short* qin_b = (unsigned short*)ws;  ws += (size_t)BB * BQ * DM * 2;
  unsigned short* kvin_b = (unsigned short*)ws; ws += (size_t)BB * TT * DM * 2;
  unsigned short* Wq_b = (unsigned short*)ws;   ws += (size_t)DM * DM * 2;
  unsigned short* Wk_b = (unsigned short*)ws;   ws += (size_t)DM * DM * 2;
  unsigned short* Wv_b = (unsigned short*)ws;   ws += (size_t)DM * DM * 2;
  unsigned short* Wo_b = (unsigned short*)ws;   ws += (size_t)DM * DM * 2;
  unsigned short* qp = (unsigned short*)ws;     ws += (size_t)BB * NH * BQ * DH * 2;
  unsigned short* kp = (unsigned short*)ws;     ws += (size_t)BB * NH * TT * DH * 2;
  unsigned short* vp = (unsigned short*)ws;     ws += (size_t)BB * NH * TT * DH * 2;
  unsigned short* ao = (unsigned short*)ws;     ws += (size_t)BB * BQ * DM * 2;
  // vt aliases kvin_b: kv_in bf16 is dead after the V projection GEMM.
  unsigned short* vt = kvin_b;

  const int qn4 = BB * BQ * DM / 4;
  const int kvn4 = BB * TT * DM / 4;
  const int wn4 = DM * DM / 4;
  cvt_f32_bf16<<<(qn4 + 255) / 256, 256, 0, stream>>>(q_in, qin_b, qn4);
  cvt_f32_bf16<<<(kvn4 + 255) / 256, 256, 0, stream>>>(kv_in, kvin_b, kvn4);
  cvt_f32_bf16<<<(wn4 + 255) / 256, 256, 0, stream>>>(Wq, Wq_b, wn4);
  cvt_f32_bf16<<<(wn4 + 255) / 256, 256, 0, stream>>>(Wk, Wk_b, wn4);
  cvt_f32_bf16<<<(wn4 + 255) / 256, 256, 0, stream>>>(Wv, Wv_b, wn4);
  cvt_f32_bf16<<<(wn4 + 255) / 256, 256, 0, stream>>>(Wo, Wo_b, wn4);

  dim3 blk(256);
  gemm_bt<0, BQ, true><<<dim3(BB * BQ / 128, DM / 128), blk, 0, stream>>>(qin_b, Wq_b, qp, nullptr);
  gemm_bt<0, TT, false><<<dim3(BB * TT / 128, DM / 128), blk, 0, stream>>>(kvin_b, Wk_b, kp, nullptr);
  gemm_bt<0, TT, false><<<dim3(BB * TT / 128, DM / 128), blk, 0, stream>>>(kvin_b, Wv_b, vp, nullptr);

  transpose_v<<<dim3(BB * NH, TT / 64), blk, 0, stream>>>(vp, vt);

  attn_kern<<<dim3(BB * NH, BQ / 128), blk, 0, stream>>>(qp, kp, vt, ao);

  gemm_bt<1, BQ, false><<<dim3(BB * BQ / 128, DM / 128), blk, 0, stream>>>(ao, Wo_b, nullptr, out);
}

// Round 7
// 302.991 us; speedup vs baseline: 1.5910x; 1.1283x over previous
//
#include <hip/hip_runtime.h>
#include <hip/hip_bf16.h>
#include <cstdint>
#include <cstddef>

#define DM 1024
#define NH 16
#define DH 64
#define BQ 1024
#define TT 4096
#define BB 4

using f32x4 = __attribute__((ext_vector_type(4))) float;
using f32x16 = __attribute__((ext_vector_type(16))) float;
using s16x8 = __attribute__((ext_vector_type(8))) short;

// native f32 -> bf16 (RNE via HW cvt)
__device__ __forceinline__ unsigned short f2bf(float f) {
  union { __hip_bfloat16 h; unsigned short u; } c;
  c.h = __float2bfloat16(f);
  return c.u;
}

// raw v_exp_f32 (no ocml range fixup — args bounded in (-inf, 8] here)
__device__ __forceinline__ float exp2_raw(float x) {
  return __builtin_amdgcn_exp2f(x);
}

__device__ __forceinline__ f32x16 zero16() {
  f32x16 z;
#pragma unroll
  for (int i = 0; i < 16; i++) z[i] = 0.f;
  return z;
}

// packed f32 pair -> u32 of 2 bf16 (lo -> [15:0], hi -> [31:16]) via HW cvt_pk.
// VALU-only asm: output feeds shfl/MFMA through compiler-visible deps (safe).
__device__ __forceinline__ int cvtpk(float lo, float hi2) {
  int r;
  asm("v_cvt_pk_bf16_f32 %0, %1, %2" : "=v"(r) : "v"(lo), "v"(hi2));
  return r;
}

// Build PV A-operand fragment (8 bf16: t = 16kk+8hi+j) from lane-local P regs.
// p[r] = P[q=lane&31][t = 32g + (r&3)+8*(r>>2)+4*hi]; RB=0 -> low 16 t's, RB=8 -> high.
// Partner exchange via __shfl_xor(...,32) (ds_bpermute; hazard-managed by compiler).
template<int RB>
__device__ __forceinline__ s16x8 mkfrag(const f32x16& p, int hi) {
  const int W1 = cvtpk(p[RB + 0], p[RB + 1]);  // hi=0:(t0,t1)   hi=1:(t4,t5)
  const int W3 = cvtpk(p[RB + 2], p[RB + 3]);  // hi=0:(t2,t3)   hi=1:(t6,t7)
  const int W2 = cvtpk(p[RB + 4], p[RB + 5]);  // hi=0:(t8,t9)   hi=1:(t12,t13)
  const int W4 = cvtpk(p[RB + 6], p[RB + 7]);  // hi=0:(t10,t11) hi=1:(t14,t15)
  const int s1 = __shfl_xor(W1, 32);
  const int s3 = __shfl_xor(W3, 32);
  const int s2 = __shfl_xor(W2, 32);
  const int s4 = __shfl_xor(W4, 32);
  union { int i[4]; s16x8 v; } u;
  u.i[0] = hi ? s2 : W1;  // t = 8hi+0,1
  u.i[1] = hi ? s4 : W3;  // t = 8hi+2,3
  u.i[2] = hi ? W2 : s1;  // t = 8hi+4,5
  u.i[3] = hi ? W4 : s3;  // t = 8hi+6,7
  return u.v;
}

__global__ void cvt_f32_bf16(const float* __restrict__ in, unsigned short* __restrict__ out, int n4) {
  int i = blockIdx.x * blockDim.x + threadIdx.x;
  if (i < n4) {
    float4 v = reinterpret_cast<const float4*>(in)[i];
    ushort4 o;
    o.x = f2bf(v.x); o.y = f2bf(v.y); o.z = f2bf(v.z); o.w = f2bf(v.w);
    reinterpret_cast<ushort4*>(out)[i] = o;
  }
}

__device__ __forceinline__ void gload_lds16(const unsigned short* g, unsigned short* l) {
  __builtin_amdgcn_global_load_lds(
      (const __attribute__((address_space(1))) unsigned int*)g,
      (__attribute__((address_space(3))) unsigned int*)l,
      16, 0, 0);
}

// C[m,n] = sum_k A[m,k] * W[n,k]   (A: Mx1024 bf16, W: 1024x1024 bf16, row-major)
// MODE 0: write bf16 scattered to [B, NH, SEQ, DH] (opt. pre-scaled); MODE 1: f32 [M, 1024]
template<int MODE, int SEQ, bool PRESCALE>
__global__ __launch_bounds__(256) void gemm_bt(const unsigned short* __restrict__ A,
                                               const unsigned short* __restrict__ W,
                                               unsigned short* __restrict__ Cb,
                                               float* __restrict__ Cf) {
  __shared__ unsigned short As[128 * 32];
  __shared__ unsigned short Bs[128 * 32];
  const int tid = threadIdx.x;
  const int wid = tid >> 6, lane = tid & 63;
  const int m0 = blockIdx.x * 128, n0 = blockIdx.y * 128;
  const int wr = wid >> 1, wc = wid & 1;
  const int fr = lane & 15;
  const int fk = (lane >> 4) * 8;

  f32x4 acc[4][4];
#pragma unroll
  for (int mt = 0; mt < 4; mt++)
#pragma unroll
    for (int nt = 0; nt < 4; nt++) acc[mt][nt] = f32x4{0.f, 0.f, 0.f, 0.f};

  const unsigned short* gA = A + (size_t)(m0 + wid * 32 + (lane >> 2)) * DM + (lane & 3) * 8;
  const unsigned short* gW = W + (size_t)(n0 + wid * 32 + (lane >> 2)) * DM + (lane & 3) * 8;
  unsigned short* lA0 = &As[(wid * 32) * 32];
  unsigned short* lA1 = &As[(wid * 32 + 16) * 32];
  unsigned short* lB0 = &Bs[(wid * 32) * 32];
  unsigned short* lB1 = &Bs[(wid * 32 + 16) * 32];

  for (int kt = 0; kt < DM / 32; ++kt) {
    gload_lds16(gA, lA0);
    gload_lds16(gA + 16 * DM, lA1);
    gload_lds16(gW, lB0);
    gload_lds16(gW + 16 * DM, lB1);
    gA += 32; gW += 32;
    __syncthreads();
    s16x8 af[4], bfv[4];
#pragma unroll
    for (int mt = 0; mt < 4; mt++)
      af[mt] = *reinterpret_cast<const s16x8*>(&As[(wr * 64 + mt * 16 + fr) * 32 + fk]);
#pragma unroll
    for (int nt = 0; nt < 4; nt++)
      bfv[nt] = *reinterpret_cast<const s16x8*>(&Bs[(wc * 64 + nt * 16 + fr) * 32 + fk]);
    __builtin_amdgcn_s_setprio(1);
#pragma unroll
    for (int mt = 0; mt < 4; mt++)
#pragma unroll
      for (int nt = 0; nt < 4; nt++)
        acc[mt][nt] = __builtin_amdgcn_mfma_f32_16x16x32_bf16(af[mt], bfv[nt], acc[mt][nt], 0, 0, 0);
    __builtin_amdgcn_s_setprio(0);
    __syncthreads();
  }

#pragma unroll
  for (int mt = 0; mt < 4; mt++) {
#pragma unroll
    for (int nt = 0; nt < 4; nt++) {
      const int col = n0 + wc * 64 + nt * 16 + fr;
#pragma unroll
      for (int r = 0; r < 4; r++) {
        const int m = m0 + wr * 64 + mt * 16 + (lane >> 4) * 4 + r;
        float v = acc[mt][nt][r];
        if constexpr (PRESCALE) v *= 0.18033688011112042f;  // 0.125 * log2(e)
        if constexpr (MODE == 0) {
          const int b = m / SEQ, sr = m % SEQ;
          const int h = col >> 6, dh = col & 63;
          Cb[((size_t)(b * NH + h) * SEQ + sr) * DH + dh] = f2bf(v);
        } else {
          Cf[(size_t)m * DM + col] = v;
        }
      }
    }
  }
}

// Transpose V: [B,H,T,DH] -> [B,H,DH,T], 64x64 tiles through swizzled LDS.
__global__ __launch_bounds__(256) void transpose_v(const unsigned short* __restrict__ vp,
                                                   unsigned short* __restrict__ vt) {
  __shared__ unsigned short tile[64 * 64];
  const int bh = blockIdx.x;
  const int t0 = blockIdx.y * 64;
  const int tid = threadIdx.x;
  const int c8 = tid & 7;
  const int r0 = tid >> 3;  // 0..31
  const size_t ibase = ((size_t)bh * TT + t0) * DH;
#pragma unroll
  for (int s = 0; s < 2; s++) {
    const int t = r0 + s * 32;
    s16x8 v = *reinterpret_cast<const s16x8*>(&vp[ibase + (size_t)t * DH + c8 * 8]);
    *reinterpret_cast<s16x8*>(&tile[t * 64 + ((c8 ^ (t & 7) ^ (t >> 3)) * 8)]) = v;
  }
  __syncthreads();
  const size_t obase = (size_t)bh * DH * TT + t0;
#pragma unroll
  for (int s = 0; s < 2; s++) {
    const int d = r0 + s * 32;
    s16x8 o;
#pragma unroll
    for (int j = 0; j < 8; j++) {
      o[j] = (short)tile[(c8 * 8 + j) * 64 + (((d >> 3) ^ j ^ c8) * 8) + (d & 7)];
    }
    *reinterpret_cast<s16x8*>(&vt[obase + (size_t)d * TT + c8 * 8]) = o;
  }
}

// Flash attention, m214-style: 4 warps x 32 q-rows, 32x32x16 MFMA, swapped QK^T,
// in-register softmax (log2 domain; Qp pre-scaled by 0.125*log2e).
// Qp/Kp: [B,NH,seq,DH] bf16; Vtg: [B,NH,DH,TT] bf16; Ob: [B,BQ,DM] bf16.
__global__ __launch_bounds__(256) void attn_kern(const unsigned short* __restrict__ Qp,
                                                 const unsigned short* __restrict__ Kp,
                                                 const unsigned short* __restrict__ Vtg,
                                                 unsigned short* __restrict__ Ob) {
  __shared__ unsigned short Ks[2][64 * 64];
  __shared__ unsigned short Vs[2][64 * 64];
  __shared__ float als[4][32];
  const int bh = blockIdx.x;  // b*NH + h
  const int b = bh >> 4, h = bh & 15;
  const int q0 = blockIdx.y * 128;
  const int tid = threadIdx.x, wid = tid >> 6, lane = tid & 63;
  const int l31 = lane & 31, hi = lane >> 5;

  // Q fragment (B-operand of swapped QK^T): lane holds Q[q=l31][dh=16kk+8hi+j]
  const size_t qrow = (size_t)bh * BQ + q0 + wid * 32 + l31;
  s16x8 qf[4];
#pragma unroll
  for (int kk = 0; kk < 4; kk++)
    qf[kk] = *reinterpret_cast<const s16x8*>(&Qp[qrow * DH + 16 * kk + 8 * hi]);

  f32x16 o0 = zero16(), o1 = zero16();
  float mrun = -3e38f, lsum = 0.f;

  const size_t kvbase = (size_t)bh * TT * DH;  // also = bh * DH * TT for Vtg
  const int srow = lane >> 3, c8 = lane & 7;

  auto stage = [&](int buf, int t0) {
#pragma unroll
    for (int s = 0; s < 2; s++) {
      const int rk = wid * 16 + s * 8 + srow;  // K row (t) / Vt row (d)
      gload_lds16(Kp + kvbase + (size_t)(t0 + rk) * DH + (c8 ^ (rk & 7)) * 8,
                  &Ks[buf][wid * 1024 + s * 512]);
      gload_lds16(Vtg + kvbase + (size_t)rk * TT + t0 + (c8 ^ (rk & 7)) * 8,
                  &Vs[buf][wid * 1024 + s * 512]);
    }
  };

  stage(0, 0);
  __syncthreads();

  const int rowA = l31;            // t/d row for group 0
  const int rowB = 32 + l31;       // group 1 (same &7 swizzle key)
  const int sw = l31 & 7;

  for (int it = 0; it < TT / 64; ++it) {
    const int cur = it & 1;
    if (it + 1 < TT / 64) stage(cur ^ 1, (it + 1) * 64);  // prefetch overlaps compute

    // S^T = K @ Q^T : D[t][q], col=lane&31=q, row t=crow(r,hi)
    f32x16 s0 = zero16(), s1 = zero16();
    __builtin_amdgcn_s_setprio(1);
#pragma unroll
    for (int kk = 0; kk < 4; kk++) {
      s16x8 kb0 = *reinterpret_cast<const s16x8*>(&Ks[cur][rowA * 64 + (((2 * kk + hi) ^ sw) * 8)]);
      s0 = __builtin_amdgcn_mfma_f32_32x32x16_bf16(kb0, qf[kk], s0, 0, 0, 0);
      s16x8 kb1 = *reinterpret_cast<const s16x8*>(&Ks[cur][rowB * 64 + (((2 * kk + hi) ^ sw) * 8)]);
      s1 = __builtin_amdgcn_mfma_f32_32x32x16_bf16(kb1, qf[kk], s1, 0, 0, 0);
    }
    __builtin_amdgcn_s_setprio(0);

    // in-lane tile max over this lane's 32 P-candidates, then partner combine
    // (lanes l / l+32 hold the same q with disjoint t-halves)
    float tm = fmaxf(s0[0], s1[0]);
#pragma unroll
    for (int r = 1; r < 16; r++) tm = fmaxf(tm, fmaxf(s0[r], s1[r]));
    tm = fmaxf(tm, __shfl_xor(tm, 32));

    // defer-max (T13, log2 domain, THR=8)
    if (__any(tm - mrun > 8.f)) {
      const float mn = fmaxf(mrun, tm);
      const float al = exp2_raw(mrun - mn);
      mrun = mn;
      lsum *= al;
      if (lane < 32) als[wid][lane] = al;   // al indexed by q
#pragma unroll
      for (int r = 0; r < 16; r++) {
        const float av = als[wid][(r & 3) + 8 * (r >> 2) + 4 * hi];
        o0[r] *= av; o1[r] *= av;
      }
    }

    // P = exp2(S - m), lane-local; lsum stays lane-partial (partner-combined at end)
#pragma unroll
    for (int r = 0; r < 16; r++) {
      s0[r] = exp2_raw(s0[r] - mrun); lsum += s0[r];
      s1[r] = exp2_raw(s1[r] - mrun); lsum += s1[r];
    }

    // in-register P -> PV A-operand (cvt_pk + shfl_xor partner exchange)
    s16x8 pa[4];
    pa[0] = mkfrag<0>(s0, hi);
    pa[1] = mkfrag<8>(s0, hi);
    pa[2] = mkfrag<0>(s1, hi);
    pa[3] = mkfrag<8>(s1, hi);

    // O += P @ V : B-operand from V^T tile rows (d), D[q][d] col=lane&31=d
    __builtin_amdgcn_s_setprio(1);
#pragma unroll
    for (int kk = 0; kk < 4; kk++) {
      s16x8 vb0 = *reinterpret_cast<const s16x8*>(&Vs[cur][rowA * 64 + (((2 * kk + hi) ^ sw) * 8)]);
      o0 = __builtin_amdgcn_mfma_f32_32x32x16_bf16(pa[kk], vb0, o0, 0, 0, 0);
      s16x8 vb1 = *reinterpret_cast<const s16x8*>(&Vs[cur][rowB * 64 + (((2 * kk + hi) ^ sw) * 8)]);
      o1 = __builtin_amdgcn_mfma_f32_32x32x16_bf16(pa[kk], vb1, o1, 0, 0, 0);
    }
    __builtin_amdgcn_s_setprio(0);

    __syncthreads();  // drains prefetch + WAR protection for buf swap
  }

  // combine partner lsum halves (lanes l / l+32 hold same q, disjoint t)
  lsum += __shfl_xor(lsum, 32);
  if (lane < 32) als[wid][lane] = lsum;

#pragma unroll
  for (int r = 0; r < 16; r++) {
    const int q = (r & 3) + 8 * (r >> 2) + 4 * hi;
    const float inv = 1.0f / als[wid][q];
    const size_t orow = ((size_t)b * BQ + q0 + wid * 32 + q) * DM + h * DH;
    Ob[orow + l31] = f2bf(o0[r] * inv);
    Ob[orow + 32 + l31] = f2bf(o1[r] * inv);
  }
}

extern "C" void kernel_launch(void* const* d_in, const int* in_sizes, int n_in,
                              void* d_out, int out_size, void* d_ws, size_t ws_size,
                              hipStream_t stream) {
  const float* q_in = (const float*)d_in[0];
  const float* kv_in = (const float*)d_in[1];
  const float* Wq = (const float*)d_in[2];
  const float* Wk = (const float*)d_in[3];
  const float* Wv = (const float*)d_in[4];
  const float* Wo = (const float*)d_in[5];
  float* out = (float*)d_out;

  char* ws = (char*)d_ws;
  unsigned short* qin_b = (unsigned short*)ws;  ws += (size_t)BB * BQ * DM * 2;
  unsigned short* kvin_b = (unsigned short*)ws; ws += (size_t)BB * TT * DM * 2;
  unsigned short* Wq_b = (unsigned short*)ws;   ws += (size_t)DM * DM * 2;
  unsigned short* Wk_b = (unsigned short*)ws;   ws += (size_t)DM * DM * 2;
  unsigned short* Wv_b = (unsigned short*)ws;   ws += (size_t)DM * DM * 2;
  unsigned short* Wo_b = (unsigned short*)ws;   ws += (size_t)DM * DM * 2;
  unsigned short* qp = (unsigned short*)ws;     ws += (size_t)BB * NH * BQ * DH * 2;
  unsigned short* kp = (unsigned short*)ws;     ws += (size_t)BB * NH * TT * DH * 2;
  unsigned short* vp = (unsigned short*)ws;     ws += (size_t)BB * NH * TT * DH * 2;
  unsigned short* ao = (unsigned short*)ws;     ws += (size_t)BB * BQ * DM * 2;
  // vt aliases kvin_b: kv_in bf16 is dead after the V projection GEMM.
  unsigned short* vt = kvin_b;

  const int qn4 = BB * BQ * DM / 4;
  const int kvn4 = BB * TT * DM / 4;
  const int wn4 = DM * DM / 4;
  cvt_f32_bf16<<<(qn4 + 255) / 256, 256, 0, stream>>>(q_in, qin_b, qn4);
  cvt_f32_bf16<<<(kvn4 + 255) / 256, 256, 0, stream>>>(kv_in, kvin_b, kvn4);
  cvt_f32_bf16<<<(wn4 + 255) / 256, 256, 0, stream>>>(Wq, Wq_b, wn4);
  cvt_f32_bf16<<<(wn4 + 255) / 256, 256, 0, stream>>>(Wk, Wk_b, wn4);
  cvt_f32_bf16<<<(wn4 + 255) / 256, 256, 0, stream>>>(Wv, Wv_b, wn4);
  cvt_f32_bf16<<<(wn4 + 255) / 256, 256, 0, stream>>>(Wo, Wo_b, wn4);

  dim3 blk(256);
  gemm_bt<0, BQ, true><<<dim3(BB * BQ / 128, DM / 128), blk, 0, stream>>>(qin_b, Wq_b, qp, nullptr);
  gemm_bt<0, TT, false><<<dim3(BB * TT / 128, DM / 128), blk, 0, stream>>>(kvin_b, Wk_b, kp, nullptr);
  gemm_bt<0, TT, false><<<dim3(BB * TT / 128, DM / 128), blk, 0, stream>>>(kvin_b, Wv_b, vp, nullptr);

  transpose_v<<<dim3(BB * NH, TT / 64), blk, 0, stream>>>(vp, vt);

  attn_kern<<<dim3(BB * NH, BQ / 128), blk, 0, stream>>>(qp, kp, vt, ao);

  gemm_bt<1, BQ, false><<<dim3(BB * BQ / 128, DM / 128), blk, 0, stream>>>(ao, Wo_b, nullptr, out);
}

// Round 8
// 295.004 us; speedup vs baseline: 1.6341x; 1.0271x over previous
//
#include <hip/hip_runtime.h>
#include <hip/hip_bf16.h>
#include <cstdint>
#include <cstddef>

#define DM 1024
#define NH 16
#define DH 64
#define BQ 1024
#define TT 4096
#define BB 4
#define TSPLIT 2048  // KV range per attention split (2 splits)

using f32x4 = __attribute__((ext_vector_type(4))) float;
using f32x16 = __attribute__((ext_vector_type(16))) float;
using s16x8 = __attribute__((ext_vector_type(8))) short;

// native f32 -> bf16 (RNE via HW cvt)
__device__ __forceinline__ unsigned short f2bf(float f) {
  union { __hip_bfloat16 h; unsigned short u; } c;
  c.h = __float2bfloat16(f);
  return c.u;
}

// raw v_exp_f32 (no ocml range fixup — args bounded in (-inf, 8] here)
__device__ __forceinline__ float exp2_raw(float x) {
  return __builtin_amdgcn_exp2f(x);
}

__device__ __forceinline__ f32x16 zero16() {
  f32x16 z;
#pragma unroll
  for (int i = 0; i < 16; i++) z[i] = 0.f;
  return z;
}

// packed f32 pair -> u32 of 2 bf16 (lo -> [15:0], hi -> [31:16]) via HW cvt_pk.
__device__ __forceinline__ int cvtpk(float lo, float hi2) {
  int r;
  asm("v_cvt_pk_bf16_f32 %0, %1, %2" : "=v"(r) : "v"(lo), "v"(hi2));
  return r;
}

// Build PV A-operand fragment (8 bf16: t = 16kk+8hi+j) from lane-local P regs.
template<int RB>
__device__ __forceinline__ s16x8 mkfrag(const f32x16& p, int hi) {
  const int W1 = cvtpk(p[RB + 0], p[RB + 1]);
  const int W3 = cvtpk(p[RB + 2], p[RB + 3]);
  const int W2 = cvtpk(p[RB + 4], p[RB + 5]);
  const int W4 = cvtpk(p[RB + 6], p[RB + 7]);
  const int s1 = __shfl_xor(W1, 32);
  const int s3 = __shfl_xor(W3, 32);
  const int s2 = __shfl_xor(W2, 32);
  const int s4 = __shfl_xor(W4, 32);
  union { int i[4]; s16x8 v; } u;
  u.i[0] = hi ? s2 : W1;
  u.i[1] = hi ? s4 : W3;
  u.i[2] = hi ? W2 : s1;
  u.i[3] = hi ? W4 : s3;
  return u.v;
}

__global__ void cvt_f32_bf16(const float* __restrict__ in, unsigned short* __restrict__ out, int n4) {
  int i = blockIdx.x * blockDim.x + threadIdx.x;
  if (i < n4) {
    float4 v = reinterpret_cast<const float4*>(in)[i];
    ushort4 o;
    o.x = f2bf(v.x); o.y = f2bf(v.y); o.z = f2bf(v.z); o.w = f2bf(v.w);
    reinterpret_cast<ushort4*>(out)[i] = o;
  }
}

__device__ __forceinline__ void gload_lds16(const unsigned short* g, unsigned short* l) {
  __builtin_amdgcn_global_load_lds(
      (const __attribute__((address_space(1))) unsigned int*)g,
      (__attribute__((address_space(3))) unsigned int*)l,
      16, 0, 0);
}

// C[m,n] = sum_k A[m,k] * W[n,k]
// MODE 0: write bf16 scattered to [B, NH, SEQ, DH] (opt. pre-scaled); MODE 1: f32 [M, 1024]
template<int MODE, int SEQ, bool PRESCALE>
__global__ __launch_bounds__(256) void gemm_bt(const unsigned short* __restrict__ A,
                                               const unsigned short* __restrict__ W,
                                               unsigned short* __restrict__ Cb,
                                               float* __restrict__ Cf) {
  __shared__ unsigned short As[128 * 32];
  __shared__ unsigned short Bs[128 * 32];
  const int tid = threadIdx.x;
  const int wid = tid >> 6, lane = tid & 63;
  const int m0 = blockIdx.x * 128, n0 = blockIdx.y * 128;
  const int wr = wid >> 1, wc = wid & 1;
  const int fr = lane & 15;
  const int fk = (lane >> 4) * 8;

  f32x4 acc[4][4];
#pragma unroll
  for (int mt = 0; mt < 4; mt++)
#pragma unroll
    for (int nt = 0; nt < 4; nt++) acc[mt][nt] = f32x4{0.f, 0.f, 0.f, 0.f};

  const unsigned short* gA = A + (size_t)(m0 + wid * 32 + (lane >> 2)) * DM + (lane & 3) * 8;
  const unsigned short* gW = W + (size_t)(n0 + wid * 32 + (lane >> 2)) * DM + (lane & 3) * 8;
  unsigned short* lA0 = &As[(wid * 32) * 32];
  unsigned short* lA1 = &As[(wid * 32 + 16) * 32];
  unsigned short* lB0 = &Bs[(wid * 32) * 32];
  unsigned short* lB1 = &Bs[(wid * 32 + 16) * 32];

  for (int kt = 0; kt < DM / 32; ++kt) {
    gload_lds16(gA, lA0);
    gload_lds16(gA + 16 * DM, lA1);
    gload_lds16(gW, lB0);
    gload_lds16(gW + 16 * DM, lB1);
    gA += 32; gW += 32;
    __syncthreads();
    s16x8 af[4], bfv[4];
#pragma unroll
    for (int mt = 0; mt < 4; mt++)
      af[mt] = *reinterpret_cast<const s16x8*>(&As[(wr * 64 + mt * 16 + fr) * 32 + fk]);
#pragma unroll
    for (int nt = 0; nt < 4; nt++)
      bfv[nt] = *reinterpret_cast<const s16x8*>(&Bs[(wc * 64 + nt * 16 + fr) * 32 + fk]);
    __builtin_amdgcn_s_setprio(1);
#pragma unroll
    for (int mt = 0; mt < 4; mt++)
#pragma unroll
      for (int nt = 0; nt < 4; nt++)
        acc[mt][nt] = __builtin_amdgcn_mfma_f32_16x16x32_bf16(af[mt], bfv[nt], acc[mt][nt], 0, 0, 0);
    __builtin_amdgcn_s_setprio(0);
    __syncthreads();
  }

#pragma unroll
  for (int mt = 0; mt < 4; mt++) {
#pragma unroll
    for (int nt = 0; nt < 4; nt++) {
      const int col = n0 + wc * 64 + nt * 16 + fr;
#pragma unroll
      for (int r = 0; r < 4; r++) {
        const int m = m0 + wr * 64 + mt * 16 + (lane >> 4) * 4 + r;
        float v = acc[mt][nt][r];
        if constexpr (PRESCALE) v *= 0.18033688011112042f;  // 0.125 * log2(e)
        if constexpr (MODE == 0) {
          const int b = m / SEQ, sr = m % SEQ;
          const int h = col >> 6, dh = col & 63;
          Cb[((size_t)(b * NH + h) * SEQ + sr) * DH + dh] = f2bf(v);
        } else {
          Cf[(size_t)m * DM + col] = v;
        }
      }
    }
  }
}

// Fused K|V projection: A = kv_in bf16 [BB*TT, 1024]; Wkv = [Wk;Wv] (2048 x 1024).
// col<1024 -> K written [B,NH,TT,DH]; col>=1024 -> V written TRANSPOSED [B,NH,DH,TT].
__global__ __launch_bounds__(256) void gemm_kv(const unsigned short* __restrict__ A,
                                               const unsigned short* __restrict__ Wkv,
                                               unsigned short* __restrict__ Kp,
                                               unsigned short* __restrict__ Vt) {
  __shared__ unsigned short As[128 * 32];
  __shared__ unsigned short Bs[128 * 32];
  const int tid = threadIdx.x;
  const int wid = tid >> 6, lane = tid & 63;
  const int m0 = blockIdx.x * 128, n0 = blockIdx.y * 128;
  const int wr = wid >> 1, wc = wid & 1;
  const int fr = lane & 15;
  const int fk = (lane >> 4) * 8;

  f32x4 acc[4][4];
#pragma unroll
  for (int mt = 0; mt < 4; mt++)
#pragma unroll
    for (int nt = 0; nt < 4; nt++) acc[mt][nt] = f32x4{0.f, 0.f, 0.f, 0.f};

  const unsigned short* gA = A + (size_t)(m0 + wid * 32 + (lane >> 2)) * DM + (lane & 3) * 8;
  const unsigned short* gW = Wkv + (size_t)(n0 + wid * 32 + (lane >> 2)) * DM + (lane & 3) * 8;
  unsigned short* lA0 = &As[(wid * 32) * 32];
  unsigned short* lA1 = &As[(wid * 32 + 16) * 32];
  unsigned short* lB0 = &Bs[(wid * 32) * 32];
  unsigned short* lB1 = &Bs[(wid * 32 + 16) * 32];

  for (int kt = 0; kt < DM / 32; ++kt) {
    gload_lds16(gA, lA0);
    gload_lds16(gA + 16 * DM, lA1);
    gload_lds16(gW, lB0);
    gload_lds16(gW + 16 * DM, lB1);
    gA += 32; gW += 32;
    __syncthreads();
    s16x8 af[4], bfv[4];
#pragma unroll
    for (int mt = 0; mt < 4; mt++)
      af[mt] = *reinterpret_cast<const s16x8*>(&As[(wr * 64 + mt * 16 + fr) * 32 + fk]);
#pragma unroll
    for (int nt = 0; nt < 4; nt++)
      bfv[nt] = *reinterpret_cast<const s16x8*>(&Bs[(wc * 64 + nt * 16 + fr) * 32 + fk]);
    __builtin_amdgcn_s_setprio(1);
#pragma unroll
    for (int mt = 0; mt < 4; mt++)
#pragma unroll
      for (int nt = 0; nt < 4; nt++)
        acc[mt][nt] = __builtin_amdgcn_mfma_f32_16x16x32_bf16(af[mt], bfv[nt], acc[mt][nt], 0, 0, 0);
    __builtin_amdgcn_s_setprio(0);
    __syncthreads();
  }

  const int klg = lane >> 4;
#pragma unroll
  for (int mt = 0; mt < 4; mt++) {
#pragma unroll
    for (int nt = 0; nt < 4; nt++) {
      const int col = n0 + wc * 64 + nt * 16 + fr;
      const int tb = m0 + wr * 64 + mt * 16 + klg * 4;  // 4 consecutive t = tb..tb+3
      const int b = tb >> 12, sr = tb & (TT - 1);
      if (col < DM) {
        const int h = col >> 6, dh = col & 63;
#pragma unroll
        for (int r = 0; r < 4; r++)
          Kp[((size_t)(b * NH + h) * TT + sr + r) * DH + dh] = f2bf(acc[mt][nt][r]);
      } else {
        const int c2 = col - DM;
        const int h = c2 >> 6, dh = c2 & 63;
        ushort4 pk;
        pk.x = f2bf(acc[mt][nt][0]);
        pk.y = f2bf(acc[mt][nt][1]);
        pk.z = f2bf(acc[mt][nt][2]);
        pk.w = f2bf(acc[mt][nt][3]);
        *reinterpret_cast<ushort4*>(&Vt[((size_t)(b * NH + h) * DH + dh) * TT + sr]) = pk;
      }
    }
  }
}

// Flash attention with T-split: each block handles TSPLIT of the KV range.
// Writes UNNORMALIZED partial O (f32) + per-row (m, l) for the combine kernel.
// Qp (pre-scaled by 0.125*log2e) / Kp: [B,NH,seq,DH] bf16; Vtg: [B,NH,DH,TT] bf16.
__global__ __launch_bounds__(256) void attn_kern(const unsigned short* __restrict__ Qp,
                                                 const unsigned short* __restrict__ Kp,
                                                 const unsigned short* __restrict__ Vtg,
                                                 float* __restrict__ Opart,
                                                 float2* __restrict__ ml) {
  __shared__ unsigned short Ks[2][64 * 64];
  __shared__ unsigned short Vs[2][64 * 64];
  __shared__ float als[4][32];
  const int bh = blockIdx.x;  // b*NH + h
  const int q0 = blockIdx.y * 128;
  const int split = blockIdx.z;
  const int t00 = split * TSPLIT;
  const int tid = threadIdx.x, wid = tid >> 6, lane = tid & 63;
  const int l31 = lane & 31, hi = lane >> 5;

  const size_t qrow = (size_t)bh * BQ + q0 + wid * 32 + l31;
  s16x8 qf[4];
#pragma unroll
  for (int kk = 0; kk < 4; kk++)
    qf[kk] = *reinterpret_cast<const s16x8*>(&Qp[qrow * DH + 16 * kk + 8 * hi]);

  f32x16 o0 = zero16(), o1 = zero16();
  float mrun = -3e38f, lsum = 0.f;

  const size_t kvbase = (size_t)bh * TT * DH;  // also = bh * DH * TT for Vtg
  const int srow = lane >> 3, c8 = lane & 7;

  auto stage = [&](int buf, int t0) {
#pragma unroll
    for (int s = 0; s < 2; s++) {
      const int rk = wid * 16 + s * 8 + srow;  // K row (t) / Vt row (d)
      gload_lds16(Kp + kvbase + (size_t)(t0 + rk) * DH + (c8 ^ (rk & 7)) * 8,
                  &Ks[buf][wid * 1024 + s * 512]);
      gload_lds16(Vtg + kvbase + (size_t)rk * TT + t0 + (c8 ^ (rk & 7)) * 8,
                  &Vs[buf][wid * 1024 + s * 512]);
    }
  };

  stage(0, t00);
  __syncthreads();

  const int rowA = l31;
  const int rowB = 32 + l31;
  const int sw = l31 & 7;

  for (int it = 0; it < TSPLIT / 64; ++it) {
    const int cur = it & 1;
    if (it + 1 < TSPLIT / 64) stage(cur ^ 1, t00 + (it + 1) * 64);

    // S^T = K @ Q^T : D[t][q], col=lane&31=q, row t=crow(r,hi)
    f32x16 s0 = zero16(), s1 = zero16();
    __builtin_amdgcn_s_setprio(1);
#pragma unroll
    for (int kk = 0; kk < 4; kk++) {
      s16x8 kb0 = *reinterpret_cast<const s16x8*>(&Ks[cur][rowA * 64 + (((2 * kk + hi) ^ sw) * 8)]);
      s0 = __builtin_amdgcn_mfma_f32_32x32x16_bf16(kb0, qf[kk], s0, 0, 0, 0);
      s16x8 kb1 = *reinterpret_cast<const s16x8*>(&Ks[cur][rowB * 64 + (((2 * kk + hi) ^ sw) * 8)]);
      s1 = __builtin_amdgcn_mfma_f32_32x32x16_bf16(kb1, qf[kk], s1, 0, 0, 0);
    }
    __builtin_amdgcn_s_setprio(0);

    float tm = fmaxf(s0[0], s1[0]);
#pragma unroll
    for (int r = 1; r < 16; r++) tm = fmaxf(tm, fmaxf(s0[r], s1[r]));
    tm = fmaxf(tm, __shfl_xor(tm, 32));

    // defer-max (T13, log2 domain, THR=8)
    if (__any(tm - mrun > 8.f)) {
      const float mn = fmaxf(mrun, tm);
      const float al = exp2_raw(mrun - mn);
      mrun = mn;
      lsum *= al;
      if (lane < 32) als[wid][lane] = al;
#pragma unroll
      for (int r = 0; r < 16; r++) {
        const float av = als[wid][(r & 3) + 8 * (r >> 2) + 4 * hi];
        o0[r] *= av; o1[r] *= av;
      }
    }

#pragma unroll
    for (int r = 0; r < 16; r++) {
      s0[r] = exp2_raw(s0[r] - mrun); lsum += s0[r];
      s1[r] = exp2_raw(s1[r] - mrun); lsum += s1[r];
    }

    s16x8 pa[4];
    pa[0] = mkfrag<0>(s0, hi);
    pa[1] = mkfrag<8>(s0, hi);
    pa[2] = mkfrag<0>(s1, hi);
    pa[3] = mkfrag<8>(s1, hi);

    __builtin_amdgcn_s_setprio(1);
#pragma unroll
    for (int kk = 0; kk < 4; kk++) {
      s16x8 vb0 = *reinterpret_cast<const s16x8*>(&Vs[cur][rowA * 64 + (((2 * kk + hi) ^ sw) * 8)]);
      o0 = __builtin_amdgcn_mfma_f32_32x32x16_bf16(pa[kk], vb0, o0, 0, 0, 0);
      s16x8 vb1 = *reinterpret_cast<const s16x8*>(&Vs[cur][rowB * 64 + (((2 * kk + hi) ^ sw) * 8)]);
      o1 = __builtin_amdgcn_mfma_f32_32x32x16_bf16(pa[kk], vb1, o1, 0, 0, 0);
    }
    __builtin_amdgcn_s_setprio(0);

    __syncthreads();
  }

  // partner-combine lsum; mrun already uniform across partner pair
  lsum += __shfl_xor(lsum, 32);
  if (lane < 32)
    ml[((size_t)split * (BB * NH) + bh) * BQ + q0 + wid * 32 + lane] = float2{mrun, lsum};

#pragma unroll
  for (int r = 0; r < 16; r++) {
    const int q = (r & 3) + 8 * (r >> 2) + 4 * hi;
    const size_t orow = (((size_t)split * (BB * NH) + bh) * BQ + q0 + wid * 32 + q) * DH;
    Opart[orow + l31] = o0[r];
    Opart[orow + 32 + l31] = o1[r];
  }
}

// Merge the two KV-splits: out = (O0*w0 + O1*w1) / (l0*w0 + l1*w1), w_i = 2^(m_i - m).
__global__ __launch_bounds__(256) void attn_combine(const float* __restrict__ Opart,
                                                    const float2* __restrict__ ml,
                                                    unsigned short* __restrict__ Ob) {
  const int gid = blockIdx.x * 256 + threadIdx.x;  // BB*NH*BQ*16 total
  const int row = gid >> 4, seg = gid & 15;
  const float2 a = ml[row];
  const float2 c = ml[BB * NH * BQ + row];
  const float m = fmaxf(a.x, c.x);
  const float w0 = exp2_raw(a.x - m), w1 = exp2_raw(c.x - m);
  const float inv = 1.0f / (a.y * w0 + c.y * w1);
  const float4 p0 = reinterpret_cast<const float4*>(Opart)[(size_t)row * 16 + seg];
  const float4 p1 = reinterpret_cast<const float4*>(Opart)[(size_t)(BB * NH * BQ) * 16 + row * 16 + seg];
  const int bh = row >> 10, q = row & (BQ - 1);
  const int b = bh >> 4, h = bh & 15;
  ushort4 o;
  o.x = f2bf((p0.x * w0 + p1.x * w1) * inv);
  o.y = f2bf((p0.y * w0 + p1.y * w1) * inv);
  o.z = f2bf((p0.z * w0 + p1.z * w1) * inv);
  o.w = f2bf((p0.w * w0 + p1.w * w1) * inv);
  *reinterpret_cast<ushort4*>(&Ob[((size_t)b * BQ + q) * DM + h * DH + seg * 4]) = o;
}

extern "C" void kernel_launch(void* const* d_in, const int* in_sizes, int n_in,
                              void* d_out, int out_size, void* d_ws, size_t ws_size,
                              hipStream_t stream) {
  const float* q_in = (const float*)d_in[0];
  const float* kv_in = (const float*)d_in[1];
  const float* Wq = (const float*)d_in[2];
  const float* Wk = (const float*)d_in[3];
  const float* Wv = (const float*)d_in[4];
  const float* Wo = (const float*)d_in[5];
  float* out = (float*)d_out;

  char* ws = (char*)d_ws;
  unsigned short* qin_b = (unsigned short*)ws;  ws += (size_t)BB * BQ * DM * 2;
  unsigned short* kvin_b = (unsigned short*)ws; ws += (size_t)BB * TT * DM * 2;
  unsigned short* Wq_b = (unsigned short*)ws;   ws += (size_t)DM * DM * 2;
  unsigned short* Wk_b = (unsigned short*)ws;   ws += (size_t)DM * DM * 2;  // [Wk;Wv] must stay adjacent
  unsigned short* Wv_b = (unsigned short*)ws;   ws += (size_t)DM * DM * 2;
  unsigned short* Wo_b = (unsigned short*)ws;   ws += (size_t)DM * DM * 2;
  unsigned short* qp = (unsigned short*)ws;     ws += (size_t)BB * NH * BQ * DH * 2;
  unsigned short* kp = (unsigned short*)ws;     ws += (size_t)BB * NH * TT * DH * 2;
  unsigned short* vt = (unsigned short*)ws;     ws += (size_t)BB * NH * DH * TT * 2;
  unsigned short* ao = (unsigned short*)ws;     ws += (size_t)BB * BQ * DM * 2;
  float* Opart = (float*)ws;                    ws += (size_t)2 * BB * NH * BQ * DH * 4;
  float2* mlb = (float2*)ws;                    ws += (size_t)2 * BB * NH * BQ * 8;

  const int qn4 = BB * BQ * DM / 4;
  const int kvn4 = BB * TT * DM / 4;
  const int wn4 = DM * DM / 4;
  cvt_f32_bf16<<<(qn4 + 255) / 256, 256, 0, stream>>>(q_in, qin_b, qn4);
  cvt_f32_bf16<<<(kvn4 + 255) / 256, 256, 0, stream>>>(kv_in, kvin_b, kvn4);
  cvt_f32_bf16<<<(wn4 + 255) / 256, 256, 0, stream>>>(Wq, Wq_b, wn4);
  cvt_f32_bf16<<<(wn4 + 255) / 256, 256, 0, stream>>>(Wk, Wk_b, wn4);
  cvt_f32_bf16<<<(wn4 + 255) / 256, 256, 0, stream>>>(Wv, Wv_b, wn4);
  cvt_f32_bf16<<<(wn4 + 255) / 256, 256, 0, stream>>>(Wo, Wo_b, wn4);

  dim3 blk(256);
  gemm_bt<0, BQ, true><<<dim3(BB * BQ / 128, DM / 128), blk, 0, stream>>>(qin_b, Wq_b, qp, nullptr);
  gemm_kv<<<dim3(BB * TT / 128, 2 * DM / 128), blk, 0, stream>>>(kvin_b, Wk_b, kp, vt);

  attn_kern<<<dim3(BB * NH, BQ / 128, 2), blk, 0, stream>>>(qp, kp, vt, Opart, mlb);
  attn_combine<<<dim3(BB * NH * BQ * 16 / 256), blk, 0, stream>>>(Opart, mlb, ao);

  gemm_bt<1, BQ, false><<<dim3(BB * BQ / 128, DM / 128), blk, 0, stream>>>(ao, Wo_b, nullptr, out);
}

// Round 9
// 277.587 us; speedup vs baseline: 1.7367x; 1.0627x over previous
//
#include <hip/hip_runtime.h>
#include <hip/hip_bf16.h>
#include <cstdint>
#include <cstddef>

#define DM 1024
#define NH 16
#define DH 64
#define BQ 1024
#define TT 4096
#define BB 4
#define TSPLIT 2048  // KV range per attention split (2 splits)

using f32x4 = __attribute__((ext_vector_type(4))) float;
using f32x16 = __attribute__((ext_vector_type(16))) float;
using s16x8 = __attribute__((ext_vector_type(8))) short;

// native f32 -> bf16 (RNE via HW cvt)
__device__ __forceinline__ unsigned short f2bf(float f) {
  union { __hip_bfloat16 h; unsigned short u; } c;
  c.h = __float2bfloat16(f);
  return c.u;
}

// raw v_exp_f32 (no ocml range fixup — args bounded in (-inf, 8] here)
__device__ __forceinline__ float exp2_raw(float x) {
  return __builtin_amdgcn_exp2f(x);
}

__device__ __forceinline__ f32x16 zero16() {
  f32x16 z;
#pragma unroll
  for (int i = 0; i < 16; i++) z[i] = 0.f;
  return z;
}

// packed f32 pair -> u32 of 2 bf16 (lo -> [15:0], hi -> [31:16]) via HW cvt_pk.
__device__ __forceinline__ int cvtpk(float lo, float hi2) {
  int r;
  asm("v_cvt_pk_bf16_f32 %0, %1, %2" : "=v"(r) : "v"(lo), "v"(hi2));
  return r;
}

// Build PV A-operand fragment (8 bf16: t = 16kk+8hi+j) from lane-local P regs.
template<int RB>
__device__ __forceinline__ s16x8 mkfrag(const f32x16& p, int hi) {
  const int W1 = cvtpk(p[RB + 0], p[RB + 1]);
  const int W3 = cvtpk(p[RB + 2], p[RB + 3]);
  const int W2 = cvtpk(p[RB + 4], p[RB + 5]);
  const int W4 = cvtpk(p[RB + 6], p[RB + 7]);
  const int s1 = __shfl_xor(W1, 32);
  const int s3 = __shfl_xor(W3, 32);
  const int s2 = __shfl_xor(W2, 32);
  const int s4 = __shfl_xor(W4, 32);
  union { int i[4]; s16x8 v; } u;
  u.i[0] = hi ? s2 : W1;
  u.i[1] = hi ? s4 : W3;
  u.i[2] = hi ? W2 : s1;
  u.i[3] = hi ? W4 : s3;
  return u.v;
}

__global__ void cvt_f32_bf16(const float* __restrict__ in, unsigned short* __restrict__ out, int n4) {
  int i = blockIdx.x * blockDim.x + threadIdx.x;
  if (i < n4) {
    float4 v = reinterpret_cast<const float4*>(in)[i];
    ushort4 o;
    o.x = f2bf(v.x); o.y = f2bf(v.y); o.z = f2bf(v.z); o.w = f2bf(v.w);
    reinterpret_cast<ushort4*>(out)[i] = o;
  }
}

__device__ __forceinline__ void gload_lds16(const unsigned short* g, unsigned short* l) {
  __builtin_amdgcn_global_load_lds(
      (const __attribute__((address_space(1))) unsigned int*)g,
      (__attribute__((address_space(3))) unsigned int*)l,
      16, 0, 0);
}

// C[m,n] = sum_k A[m,k] * W[n,k]
// MODE 0: write bf16 scattered to [B, NH, SEQ, DH] (opt. pre-scaled); MODE 1: f32 [M, 1024]
template<int MODE, int SEQ, bool PRESCALE>
__global__ __launch_bounds__(256) void gemm_bt(const unsigned short* __restrict__ A,
                                               const unsigned short* __restrict__ W,
                                               unsigned short* __restrict__ Cb,
                                               float* __restrict__ Cf) {
  __shared__ unsigned short As[128 * 32];
  __shared__ unsigned short Bs[128 * 32];
  const int tid = threadIdx.x;
  const int wid = tid >> 6, lane = tid & 63;
  const int m0 = blockIdx.x * 128, n0 = blockIdx.y * 128;
  const int wr = wid >> 1, wc = wid & 1;
  const int fr = lane & 15;
  const int fk = (lane >> 4) * 8;

  f32x4 acc[4][4];
#pragma unroll
  for (int mt = 0; mt < 4; mt++)
#pragma unroll
    for (int nt = 0; nt < 4; nt++) acc[mt][nt] = f32x4{0.f, 0.f, 0.f, 0.f};

  const unsigned short* gA = A + (size_t)(m0 + wid * 32 + (lane >> 2)) * DM + (lane & 3) * 8;
  const unsigned short* gW = W + (size_t)(n0 + wid * 32 + (lane >> 2)) * DM + (lane & 3) * 8;
  unsigned short* lA0 = &As[(wid * 32) * 32];
  unsigned short* lA1 = &As[(wid * 32 + 16) * 32];
  unsigned short* lB0 = &Bs[(wid * 32) * 32];
  unsigned short* lB1 = &Bs[(wid * 32 + 16) * 32];

  for (int kt = 0; kt < DM / 32; ++kt) {
    gload_lds16(gA, lA0);
    gload_lds16(gA + 16 * DM, lA1);
    gload_lds16(gW, lB0);
    gload_lds16(gW + 16 * DM, lB1);
    gA += 32; gW += 32;
    __syncthreads();
    s16x8 af[4], bfv[4];
#pragma unroll
    for (int mt = 0; mt < 4; mt++)
      af[mt] = *reinterpret_cast<const s16x8*>(&As[(wr * 64 + mt * 16 + fr) * 32 + fk]);
#pragma unroll
    for (int nt = 0; nt < 4; nt++)
      bfv[nt] = *reinterpret_cast<const s16x8*>(&Bs[(wc * 64 + nt * 16 + fr) * 32 + fk]);
    __builtin_amdgcn_s_setprio(1);
#pragma unroll
    for (int mt = 0; mt < 4; mt++)
#pragma unroll
      for (int nt = 0; nt < 4; nt++)
        acc[mt][nt] = __builtin_amdgcn_mfma_f32_16x16x32_bf16(af[mt], bfv[nt], acc[mt][nt], 0, 0, 0);
    __builtin_amdgcn_s_setprio(0);
    __syncthreads();
  }

#pragma unroll
  for (int mt = 0; mt < 4; mt++) {
#pragma unroll
    for (int nt = 0; nt < 4; nt++) {
      const int col = n0 + wc * 64 + nt * 16 + fr;
#pragma unroll
      for (int r = 0; r < 4; r++) {
        const int m = m0 + wr * 64 + mt * 16 + (lane >> 4) * 4 + r;
        float v = acc[mt][nt][r];
        if constexpr (PRESCALE) v *= 0.18033688011112042f;  // 0.125 * log2(e)
        if constexpr (MODE == 0) {
          const int b = m / SEQ, sr = m % SEQ;
          const int h = col >> 6, dh = col & 63;
          Cb[((size_t)(b * NH + h) * SEQ + sr) * DH + dh] = f2bf(v);
        } else {
          Cf[(size_t)m * DM + col] = v;
        }
      }
    }
  }
}

// Fused K|V projection: A = kv_in bf16 [BB*TT, 1024]; Wkv = [Wk;Wv] (2048 x 1024).
// col<1024 -> K written [B,NH,TT,DH]; col>=1024 -> V written TRANSPOSED [B,NH,DH,TT].
__global__ __launch_bounds__(256) void gemm_kv(const unsigned short* __restrict__ A,
                                               const unsigned short* __restrict__ Wkv,
                                               unsigned short* __restrict__ Kp,
                                               unsigned short* __restrict__ Vt) {
  __shared__ unsigned short As[128 * 32];
  __shared__ unsigned short Bs[128 * 32];
  const int tid = threadIdx.x;
  const int wid = tid >> 6, lane = tid & 63;
  const int m0 = blockIdx.x * 128, n0 = blockIdx.y * 128;
  const int wr = wid >> 1, wc = wid & 1;
  const int fr = lane & 15;
  const int fk = (lane >> 4) * 8;

  f32x4 acc[4][4];
#pragma unroll
  for (int mt = 0; mt < 4; mt++)
#pragma unroll
    for (int nt = 0; nt < 4; nt++) acc[mt][nt] = f32x4{0.f, 0.f, 0.f, 0.f};

  const unsigned short* gA = A + (size_t)(m0 + wid * 32 + (lane >> 2)) * DM + (lane & 3) * 8;
  const unsigned short* gW = Wkv + (size_t)(n0 + wid * 32 + (lane >> 2)) * DM + (lane & 3) * 8;
  unsigned short* lA0 = &As[(wid * 32) * 32];
  unsigned short* lA1 = &As[(wid * 32 + 16) * 32];
  unsigned short* lB0 = &Bs[(wid * 32) * 32];
  unsigned short* lB1 = &Bs[(wid * 32 + 16) * 32];

  for (int kt = 0; kt < DM / 32; ++kt) {
    gload_lds16(gA, lA0);
    gload_lds16(gA + 16 * DM, lA1);
    gload_lds16(gW, lB0);
    gload_lds16(gW + 16 * DM, lB1);
    gA += 32; gW += 32;
    __syncthreads();
    s16x8 af[4], bfv[4];
#pragma unroll
    for (int mt = 0; mt < 4; mt++)
      af[mt] = *reinterpret_cast<const s16x8*>(&As[(wr * 64 + mt * 16 + fr) * 32 + fk]);
#pragma unroll
    for (int nt = 0; nt < 4; nt++)
      bfv[nt] = *reinterpret_cast<const s16x8*>(&Bs[(wc * 64 + nt * 16 + fr) * 32 + fk]);
    __builtin_amdgcn_s_setprio(1);
#pragma unroll
    for (int mt = 0; mt < 4; mt++)
#pragma unroll
      for (int nt = 0; nt < 4; nt++)
        acc[mt][nt] = __builtin_amdgcn_mfma_f32_16x16x32_bf16(af[mt], bfv[nt], acc[mt][nt], 0, 0, 0);
    __builtin_amdgcn_s_setprio(0);
    __syncthreads();
  }

  const int klg = lane >> 4;
#pragma unroll
  for (int mt = 0; mt < 4; mt++) {
#pragma unroll
    for (int nt = 0; nt < 4; nt++) {
      const int col = n0 + wc * 64 + nt * 16 + fr;
      const int tb = m0 + wr * 64 + mt * 16 + klg * 4;  // 4 consecutive t = tb..tb+3
      const int b = tb >> 12, sr = tb & (TT - 1);
      if (col < DM) {
        const int h = col >> 6, dh = col & 63;
#pragma unroll
        for (int r = 0; r < 4; r++)
          Kp[((size_t)(b * NH + h) * TT + sr + r) * DH + dh] = f2bf(acc[mt][nt][r]);
      } else {
        const int c2 = col - DM;
        const int h = c2 >> 6, dh = c2 & 63;
        ushort4 pk;
        pk.x = f2bf(acc[mt][nt][0]);
        pk.y = f2bf(acc[mt][nt][1]);
        pk.z = f2bf(acc[mt][nt][2]);
        pk.w = f2bf(acc[mt][nt][3]);
        *reinterpret_cast<ushort4*>(&Vt[((size_t)(b * NH + h) * DH + dh) * TT + sr]) = pk;
      }
    }
  }
}

// Flash attention, 8 warps x 32 q-rows (QBLK=256), T-split over KV range.
// Writes UNNORMALIZED partial O (f32) + per-row (m, l) for the combine kernel.
// Qp (pre-scaled by 0.125*log2e) / Kp: [B,NH,seq,DH] bf16; Vtg: [B,NH,DH,TT] bf16.
__global__ __launch_bounds__(512) void attn_kern(const unsigned short* __restrict__ Qp,
                                                 const unsigned short* __restrict__ Kp,
                                                 const unsigned short* __restrict__ Vtg,
                                                 float* __restrict__ Opart,
                                                 float2* __restrict__ ml) {
  __shared__ unsigned short Ks[2][64 * 64];
  __shared__ unsigned short Vs[2][64 * 64];
  __shared__ float als[8][32];
  const int bh = blockIdx.x;  // b*NH + h
  const int q0 = blockIdx.y * 256;
  const int split = blockIdx.z;
  const int t00 = split * TSPLIT;
  const int tid = threadIdx.x, wid = tid >> 6, lane = tid & 63;
  const int l31 = lane & 31, hi = lane >> 5;

  const size_t qrow = (size_t)bh * BQ + q0 + wid * 32 + l31;
  s16x8 qf[4];
#pragma unroll
  for (int kk = 0; kk < 4; kk++)
    qf[kk] = *reinterpret_cast<const s16x8*>(&Qp[qrow * DH + 16 * kk + 8 * hi]);

  f32x16 o0 = zero16(), o1 = zero16();
  float mrun = -3e38f, lsum = 0.f;

  const size_t kvbase = (size_t)bh * TT * DH;  // also = bh * DH * TT for Vtg
  const int rk = tid >> 3;   // 0..63: K row (t) / Vt row (d)
  const int c8 = tid & 7;    // 16B chunk

  // one K + one V gload_lds per thread covers the whole 64x64 tile pair.
  // wave w stages rows 8w..8w+7 (wave-uniform LDS base + lane*16B, linear).
  auto stage = [&](int buf, int t0) {
    gload_lds16(Kp + kvbase + (size_t)(t0 + rk) * DH + (c8 ^ (rk & 7)) * 8,
                &Ks[buf][wid * 512]);
    gload_lds16(Vtg + kvbase + (size_t)rk * TT + t0 + (c8 ^ (rk & 7)) * 8,
                &Vs[buf][wid * 512]);
  };

  stage(0, t00);
  __syncthreads();

  const int rowA = l31;
  const int rowB = 32 + l31;
  const int sw = l31 & 7;

  for (int it = 0; it < TSPLIT / 64; ++it) {
    const int cur = it & 1;
    if (it + 1 < TSPLIT / 64) stage(cur ^ 1, t00 + (it + 1) * 64);

    // S^T = K @ Q^T : D[t][q], col=lane&31=q, row t=crow(r,hi)
    f32x16 s0 = zero16(), s1 = zero16();
    __builtin_amdgcn_s_setprio(1);
#pragma unroll
    for (int kk = 0; kk < 4; kk++) {
      s16x8 kb0 = *reinterpret_cast<const s16x8*>(&Ks[cur][rowA * 64 + (((2 * kk + hi) ^ sw) * 8)]);
      s0 = __builtin_amdgcn_mfma_f32_32x32x16_bf16(kb0, qf[kk], s0, 0, 0, 0);
      s16x8 kb1 = *reinterpret_cast<const s16x8*>(&Ks[cur][rowB * 64 + (((2 * kk + hi) ^ sw) * 8)]);
      s1 = __builtin_amdgcn_mfma_f32_32x32x16_bf16(kb1, qf[kk], s1, 0, 0, 0);
    }
    __builtin_amdgcn_s_setprio(0);

    float tm = fmaxf(s0[0], s1[0]);
#pragma unroll
    for (int r = 1; r < 16; r++) tm = fmaxf(tm, fmaxf(s0[r], s1[r]));
    tm = fmaxf(tm, __shfl_xor(tm, 32));

    // defer-max (T13, log2 domain, THR=8)
    if (__any(tm - mrun > 8.f)) {
      const float mn = fmaxf(mrun, tm);
      const float al = exp2_raw(mrun - mn);
      mrun = mn;
      lsum *= al;
      if (lane < 32) als[wid][lane] = al;
#pragma unroll
      for (int r = 0; r < 16; r++) {
        const float av = als[wid][(r & 3) + 8 * (r >> 2) + 4 * hi];
        o0[r] *= av; o1[r] *= av;
      }
    }

#pragma unroll
    for (int r = 0; r < 16; r++) {
      s0[r] = exp2_raw(s0[r] - mrun); lsum += s0[r];
      s1[r] = exp2_raw(s1[r] - mrun); lsum += s1[r];
    }

    s16x8 pa[4];
    pa[0] = mkfrag<0>(s0, hi);
    pa[1] = mkfrag<8>(s0, hi);
    pa[2] = mkfrag<0>(s1, hi);
    pa[3] = mkfrag<8>(s1, hi);

    __builtin_amdgcn_s_setprio(1);
#pragma unroll
    for (int kk = 0; kk < 4; kk++) {
      s16x8 vb0 = *reinterpret_cast<const s16x8*>(&Vs[cur][rowA * 64 + (((2 * kk + hi) ^ sw) * 8)]);
      o0 = __builtin_amdgcn_mfma_f32_32x32x16_bf16(pa[kk], vb0, o0, 0, 0, 0);
      s16x8 vb1 = *reinterpret_cast<const s16x8*>(&Vs[cur][rowB * 64 + (((2 * kk + hi) ^ sw) * 8)]);
      o1 = __builtin_amdgcn_mfma_f32_32x32x16_bf16(pa[kk], vb1, o1, 0, 0, 0);
    }
    __builtin_amdgcn_s_setprio(0);

    __syncthreads();
  }

  // partner-combine lsum; mrun already uniform across partner pair
  lsum += __shfl_xor(lsum, 32);
  if (lane < 32)
    ml[((size_t)split * (BB * NH) + bh) * BQ + q0 + wid * 32 + lane] = float2{mrun, lsum};

#pragma unroll
  for (int r = 0; r < 16; r++) {
    const int q = (r & 3) + 8 * (r >> 2) + 4 * hi;
    const size_t orow = (((size_t)split * (BB * NH) + bh) * BQ + q0 + wid * 32 + q) * DH;
    Opart[orow + l31] = o0[r];
    Opart[orow + 32 + l31] = o1[r];
  }
}

// Merge the two KV-splits: out = (O0*w0 + O1*w1) / (l0*w0 + l1*w1), w_i = 2^(m_i - m).
__global__ __launch_bounds__(256) void attn_combine(const float* __restrict__ Opart,
                                                    const float2* __restrict__ ml,
                                                    unsigned short* __restrict__ Ob) {
  const int gid = blockIdx.x * 256 + threadIdx.x;  // BB*NH*BQ*16 total
  const int row = gid >> 4, seg = gid & 15;
  const float2 a = ml[row];
  const float2 c = ml[BB * NH * BQ + row];
  const float m = fmaxf(a.x, c.x);
  const float w0 = exp2_raw(a.x - m), w1 = exp2_raw(c.x - m);
  const float inv = 1.0f / (a.y * w0 + c.y * w1);
  const float4 p0 = reinterpret_cast<const float4*>(Opart)[(size_t)row * 16 + seg];
  const float4 p1 = reinterpret_cast<const float4*>(Opart)[(size_t)(BB * NH * BQ) * 16 + row * 16 + seg];
  const int bh = row >> 10, q = row & (BQ - 1);
  const int b = bh >> 4, h = bh & 15;
  ushort4 o;
  o.x = f2bf((p0.x * w0 + p1.x * w1) * inv);
  o.y = f2bf((p0.y * w0 + p1.y * w1) * inv);
  o.z = f2bf((p0.z * w0 + p1.z * w1) * inv);
  o.w = f2bf((p0.w * w0 + p1.w * w1) * inv);
  *reinterpret_cast<ushort4*>(&Ob[((size_t)b * BQ + q) * DM + h * DH + seg * 4]) = o;
}

extern "C" void kernel_launch(void* const* d_in, const int* in_sizes, int n_in,
                              void* d_out, int out_size, void* d_ws, size_t ws_size,
                              hipStream_t stream) {
  const float* q_in = (const float*)d_in[0];
  const float* kv_in = (const float*)d_in[1];
  const float* Wq = (const float*)d_in[2];
  const float* Wk = (const float*)d_in[3];
  const float* Wv = (const float*)d_in[4];
  const float* Wo = (const float*)d_in[5];
  float* out = (float*)d_out;

  char* ws = (char*)d_ws;
  unsigned short* qin_b = (unsigned short*)ws;  ws += (size_t)BB * BQ * DM * 2;
  unsigned short* kvin_b = (unsigned short*)ws; ws += (size_t)BB * TT * DM * 2;
  unsigned short* Wq_b = (unsigned short*)ws;   ws += (size_t)DM * DM * 2;
  unsigned short* Wk_b = (unsigned short*)ws;   ws += (size_t)DM * DM * 2;  // [Wk;Wv] must stay adjacent
  unsigned short* Wv_b = (unsigned short*)ws;   ws += (size_t)DM * DM * 2;
  unsigned short* Wo_b = (unsigned short*)ws;   ws += (size_t)DM * DM * 2;
  unsigned short* qp = (unsigned short*)ws;     ws += (size_t)BB * NH * BQ * DH * 2;
  unsigned short* kp = (unsigned short*)ws;     ws += (size_t)BB * NH * TT * DH * 2;
  unsigned short* vt = (unsigned short*)ws;     ws += (size_t)BB * NH * DH * TT * 2;
  unsigned short* ao = (unsigned short*)ws;     ws += (size_t)BB * BQ * DM * 2;
  float* Opart = (float*)ws;                    ws += (size_t)2 * BB * NH * BQ * DH * 4;
  float2* mlb = (float2*)ws;                    ws += (size_t)2 * BB * NH * BQ * 8;

  const int qn4 = BB * BQ * DM / 4;
  const int kvn4 = BB * TT * DM / 4;
  const int wn4 = DM * DM / 4;
  cvt_f32_bf16<<<(qn4 + 255) / 256, 256, 0, stream>>>(q_in, qin_b, qn4);
  cvt_f32_bf16<<<(kvn4 + 255) / 256, 256, 0, stream>>>(kv_in, kvin_b, kvn4);
  cvt_f32_bf16<<<(wn4 + 255) / 256, 256, 0, stream>>>(Wq, Wq_b, wn4);
  cvt_f32_bf16<<<(wn4 + 255) / 256, 256, 0, stream>>>(Wk, Wk_b, wn4);
  cvt_f32_bf16<<<(wn4 + 255) / 256, 256, 0, stream>>>(Wv, Wv_b, wn4);
  cvt_f32_bf16<<<(wn4 + 255) / 256, 256, 0, stream>>>(Wo, Wo_b, wn4);

  dim3 blk(256);
  gemm_bt<0, BQ, true><<<dim3(BB * BQ / 128, DM / 128), blk, 0, stream>>>(qin_b, Wq_b, qp, nullptr);
  gemm_kv<<<dim3(BB * TT / 128, 2 * DM / 128), blk, 0, stream>>>(kvin_b, Wk_b, kp, vt);

  attn_kern<<<dim3(BB * NH, BQ / 256, 2), dim3(512), 0, stream>>>(qp, kp, vt, Opart, mlb);
  attn_combine<<<dim3(BB * NH * BQ * 16 / 256), blk, 0, stream>>>(Opart, mlb, ao);

  gemm_bt<1, BQ, false><<<dim3(BB * BQ / 128, DM / 128), blk, 0, stream>>>(ao, Wo_b, nullptr, out);
}